// Round 1
// baseline (433.900 us; speedup 1.0000x reference)
//
#include <hip/hip_runtime.h>
#include <math.h>

// Problem constants
constexpr int Bb = 4, Ll = 2048, Dd = 256, Nn = 16;
constexpr int ML = Bb * Ll;            // 8192 rows (b,l)
constexpr int NC = 32, LCH = Ll / NC;  // 32 chunks of 64

// Workspace layout (float offsets)
constexpr size_t OFF_XZ  = 0;                                   // [8192][1024] xz both dirs
constexpr size_t OFF_XC  = OFF_XZ  + (size_t)ML * 1024;         // [2][8192][256] conv+silu out
constexpr size_t OFF_DT  = OFF_XC  + (size_t)2 * ML * 256;      // [2][8192][256] dt (softplus applied)
constexpr size_t OFF_DBC = OFF_DT  + (size_t)2 * ML * 256;      // [16384][48] xproj out (dtraw|B|C)
constexpr size_t OFF_Y   = OFF_DBC + (size_t)2 * ML * 48;       // [8192][512] gated y (f|r)
constexpr size_t OFF_AP  = OFF_Y   + (size_t)ML * 512;          // [2][4][32][4096] chunk A-prod
constexpr size_t OFF_HE  = OFF_AP  + (size_t)2 * Bb * NC * Dd * Nn; // chunk h_end -> h_start
constexpr size_t OFF_W1  = OFF_HE  + (size_t)2 * Bb * NC * Dd * Nn; // [1024][256] packed in_w
constexpr size_t OFF_W2  = OFF_W1  + (size_t)1024 * 256;        // [256][512] packed out_w
constexpr size_t OFF_B3  = OFF_W2  + (size_t)256 * 512;         // [96][256] packed xproj_w
// total = 24,272,896 floats = ~92.6 MiB

__global__ __launch_bounds__(256) void pack_weights(
    const float* __restrict__ f_in_w, const float* __restrict__ r_in_w,
    const float* __restrict__ f_out_w, const float* __restrict__ r_out_w,
    const float* __restrict__ f_xp, const float* __restrict__ r_xp,
    float* __restrict__ W1, float* __restrict__ W2, float* __restrict__ B3)
{
    int i = blockIdx.x * 256 + threadIdx.x;
    if (i < 131072) { W1[i] = f_in_w[i]; W1[131072 + i] = r_in_w[i]; }
    if (i < 65536) {
        int e = i >> 8, k = i & 255;
        W2[e * 512 + k]       = f_out_w[i];
        W2[e * 512 + 256 + k] = r_out_w[i];
    }
    if (i < 12288) { B3[i] = f_xp[i]; B3[12288 + i] = r_xp[i]; }
}

// Generic fp32 NT GEMM: C[M][N] = A[M][K] (row-major) * B[N][K]^T (row-major, K contiguous)
// For M-blocks beyond bSwitchM, B is offset by bAltOff (dir-dependent weights).
__global__ __launch_bounds__(256) void gemm_nt(
    const float* __restrict__ A, const float* __restrict__ Bmat,
    float* __restrict__ C, int M, int N, int K, int bSwitchM, int bAltOff)
{
    constexpr int BM = 64, BN = 64, BK = 32, PK = 36;  // PK: padded row stride in LDS
    __shared__ float As[BM * PK];
    __shared__ float Bs[BN * PK];
    int m0 = blockIdx.y * BM, n0 = blockIdx.x * BN;
    const float* Bp = Bmat + ((m0 >= bSwitchM) ? bAltOff : 0);
    int t  = threadIdx.x;
    int tx = t & 15, ty = t >> 4;
    int lr  = t >> 3;          // 0..31
    int lc4 = (t & 7) * 4;     // 0,4,..,28
    float acc[4][4] = {};
    for (int k0 = 0; k0 < K; k0 += BK) {
        float4 av0 = *(const float4*)(A + (size_t)(m0 + lr)      * K + k0 + lc4);
        float4 av1 = *(const float4*)(A + (size_t)(m0 + lr + 32) * K + k0 + lc4);
        float4 bv0 = make_float4(0.f, 0.f, 0.f, 0.f), bv1 = bv0;
        if (n0 + lr      < N) bv0 = *(const float4*)(Bp + (size_t)(n0 + lr)      * K + k0 + lc4);
        if (n0 + lr + 32 < N) bv1 = *(const float4*)(Bp + (size_t)(n0 + lr + 32) * K + k0 + lc4);
        __syncthreads();
        *(float4*)(As + lr * PK + lc4)        = av0;
        *(float4*)(As + (lr + 32) * PK + lc4) = av1;
        *(float4*)(Bs + lr * PK + lc4)        = bv0;
        *(float4*)(Bs + (lr + 32) * PK + lc4) = bv1;
        __syncthreads();
        #pragma unroll
        for (int kq = 0; kq < BK / 4; ++kq) {
            float4 a4[4], b4[4];
            #pragma unroll
            for (int i = 0; i < 4; i++) a4[i] = *(const float4*)(As + (ty * 4 + i) * PK + kq * 4);
            #pragma unroll
            for (int j = 0; j < 4; j++) b4[j] = *(const float4*)(Bs + (tx * 4 + j) * PK + kq * 4);
            #pragma unroll
            for (int i = 0; i < 4; i++)
                #pragma unroll
                for (int j = 0; j < 4; j++)
                    acc[i][j] += a4[i].x * b4[j].x + a4[i].y * b4[j].y +
                                 a4[i].z * b4[j].z + a4[i].w * b4[j].w;
        }
    }
    #pragma unroll
    for (int i = 0; i < 4; i++) {
        int m = m0 + ty * 4 + i;
        #pragma unroll
        for (int j = 0; j < 4; j++) {
            int n = n0 + tx * 4 + j;
            if (n < N) C[(size_t)m * N + n] = acc[i][j];
        }
    }
}

// Depthwise conv width-2 + SiLU. dir 0 taps (l-1, l); dir 1 taps (l+1, l) in original order.
__global__ __launch_bounds__(256) void conv_silu_k(
    const float* __restrict__ xz,
    const float* __restrict__ fw, const float* __restrict__ fb,
    const float* __restrict__ rw, const float* __restrict__ rb,
    float* __restrict__ xc)
{
    int i = blockIdx.x * 256 + threadIdx.x;     // 0 .. 2*8192*64-1 (float4 granularity)
    int dir = i >> 19;
    int r   = i & 524287;
    int bl  = r >> 6;
    int l   = bl & 2047;
    int d4  = (r & 63) * 4;
    const float* cw = dir ? rw : fw;
    const float* cb = dir ? rb : fb;
    size_t rowc = (size_t)bl * 1024 + dir * 512 + d4;
    float4 cur = *(const float4*)(xz + rowc);
    float4 prv = make_float4(0.f, 0.f, 0.f, 0.f);
    if (dir == 0) { if (l > 0)      prv = *(const float4*)(xz + rowc - 1024); }
    else          { if (l < Ll - 1) prv = *(const float4*)(xz + rowc + 1024); }
    float pv[4] = {prv.x, prv.y, prv.z, prv.w};
    float cv[4] = {cur.x, cur.y, cur.z, cur.w};
    float out[4];
    #pragma unroll
    for (int j = 0; j < 4; j++) {
        float v = pv[j] * cw[(d4 + j) * 2] + cv[j] * cw[(d4 + j) * 2 + 1] + cb[d4 + j];
        out[j] = v / (1.f + __expf(-v));
    }
    *(float4*)(xc + (size_t)(dir * ML + bl) * 256 + d4) = make_float4(out[0], out[1], out[2], out[3]);
}

// dt[d] = softplus(sum_r dbc[r]*dt_w[d,r] + dt_b[d])
__global__ __launch_bounds__(256) void dt_kernel(
    const float* __restrict__ dbc,
    const float* __restrict__ fw, const float* __restrict__ fb,
    const float* __restrict__ rw, const float* __restrict__ rb,
    float* __restrict__ dt)
{
    int m = blockIdx.x;          // 0..16383 = dir*8192 + b*2048 + l
    int d = threadIdx.x;
    int dir = m >> 13;
    __shared__ float s[16];
    if (d < 16) s[d] = dbc[(size_t)m * 48 + d];
    __syncthreads();
    const float* w = (dir ? rw : fw) + d * 16;
    float acc = (dir ? rb : fb)[d];
    #pragma unroll
    for (int r = 0; r < 16; r++) acc += s[r] * w[r];
    float sp = (acc > 20.f) ? acc : log1pf(__expf(acc));
    dt[(size_t)m * 256 + d] = sp;
}

// Chunked scan pass 1: per-chunk local scan from h=0, record prod(dA) and local h_end.
__global__ __launch_bounds__(256) void scan1(
    const float* __restrict__ dt, const float* __restrict__ xc,
    const float* __restrict__ dbc,
    const float* __restrict__ fA, const float* __restrict__ rA,
    float* __restrict__ aprod, float* __restrict__ hend)
{
    int blk = blockIdx.x;                       // dir*2048 + b*512 + c*16 + dblk
    int dblk = blk & 15, c = (blk >> 4) & 31, b = (blk >> 9) & 3, dir = blk >> 11;
    int t = threadIdx.x;
    int d = dblk * 16 + (t >> 4), n = t & 15;   // n in low 4 lane bits (shuffle-reducible)
    float Ac = -__expf((dir ? rA : fA)[d * 16 + n]);
    float h = 0.f, ap = 1.f;
    int mbase = dir * ML + b * Ll;
    int s0 = c * LCH;
    for (int s = s0; s < s0 + LCH; ++s) {
        int l = dir ? (Ll - 1 - s) : s;
        int m = mbase + l;
        float dtv = dt[(size_t)m * Dd + d];
        float xcv = xc[(size_t)m * Dd + d];
        float bm  = dbc[(size_t)m * 48 + 16 + n];
        float da  = __expf(dtv * Ac);
        h  = fmaf(da, h, dtv * bm * xcv);
        ap *= da;
    }
    int idx = blk * 256 + t;
    aprod[idx] = ap;
    hend[idx]  = h;
}

// Pass 2: serial combine across chunks; overwrite hend with h_start per chunk.
__global__ __launch_bounds__(256) void scan2(
    const float* __restrict__ aprod, float* __restrict__ hend)
{
    int i = blockIdx.x * 256 + threadIdx.x;   // 0..32767 = dir*16384 + b*4096 + dn
    int dn = i & 4095, b = (i >> 12) & 3, dir = i >> 14;
    size_t base = ((size_t)(dir * 4 + b)) * NC * 4096 + dn;
    float h = 0.f;
    for (int c = 0; c < NC; c++) {
        size_t idx = base + (size_t)c * 4096;
        float ap = aprod[idx];
        float hl = hend[idx];
        hend[idx] = h;                         // h_start for this chunk
        h = fmaf(ap, h, hl);
    }
}

// Pass 3: replay chunk from h_start, emit y = (C.h + D*xc) * silu(z)
__global__ __launch_bounds__(256) void scan3(
    const float* __restrict__ dt, const float* __restrict__ xc,
    const float* __restrict__ dbc, const float* __restrict__ xz,
    const float* __restrict__ fA, const float* __restrict__ rA,
    const float* __restrict__ fDp, const float* __restrict__ rDp,
    const float* __restrict__ hstart, float* __restrict__ y)
{
    int blk = blockIdx.x;
    int dblk = blk & 15, c = (blk >> 4) & 31, b = (blk >> 9) & 3, dir = blk >> 11;
    int t = threadIdx.x;
    int d = dblk * 16 + (t >> 4), n = t & 15;
    float Ac = -__expf((dir ? rA : fA)[d * 16 + n]);
    float Dp = (dir ? rDp : fDp)[d];
    float h = hstart[blk * 256 + t];
    int mbase = dir * ML + b * Ll;
    int s0 = c * LCH;
    for (int s = s0; s < s0 + LCH; ++s) {
        int l = dir ? (Ll - 1 - s) : s;
        int m = mbase + l;
        int bl = b * Ll + l;
        float dtv = dt[(size_t)m * Dd + d];
        float xcv = xc[(size_t)m * Dd + d];
        float bm  = dbc[(size_t)m * 48 + 16 + n];
        float cm  = dbc[(size_t)m * 48 + 32 + n];
        float da  = __expf(dtv * Ac);
        h = fmaf(da, h, dtv * bm * xcv);
        float yp = h * cm;
        yp += __shfl_xor(yp, 1);
        yp += __shfl_xor(yp, 2);
        yp += __shfl_xor(yp, 4);
        yp += __shfl_xor(yp, 8);
        if (n == 0) {
            float z  = xz[(size_t)bl * 1024 + dir * 512 + 256 + d];
            float sz = z / (1.f + __expf(-z));
            y[(size_t)bl * 512 + dir * 256 + d] = (yp + Dp * xcv) * sz;
        }
    }
}

extern "C" void kernel_launch(void* const* d_in, const int* in_sizes, int n_in,
                              void* d_out, int out_size, void* d_ws, size_t ws_size,
                              hipStream_t stream)
{
    const float* x        = (const float*)d_in[0];
    const float* f_in_w   = (const float*)d_in[1];
    const float* f_conv_w = (const float*)d_in[2];
    const float* f_conv_b = (const float*)d_in[3];
    const float* f_xproj  = (const float*)d_in[4];
    const float* f_dt_w   = (const float*)d_in[5];
    const float* f_dt_b   = (const float*)d_in[6];
    const float* f_A_log  = (const float*)d_in[7];
    const float* f_D      = (const float*)d_in[8];
    const float* f_out_w  = (const float*)d_in[9];
    const float* r_in_w   = (const float*)d_in[10];
    const float* r_conv_w = (const float*)d_in[11];
    const float* r_conv_b = (const float*)d_in[12];
    const float* r_xproj  = (const float*)d_in[13];
    const float* r_dt_w   = (const float*)d_in[14];
    const float* r_dt_b   = (const float*)d_in[15];
    const float* r_A_log  = (const float*)d_in[16];
    const float* r_D      = (const float*)d_in[17];
    const float* r_out_w  = (const float*)d_in[18];

    float* ws  = (float*)d_ws;
    float* xz  = ws + OFF_XZ;
    float* xcb = ws + OFF_XC;
    float* dtb = ws + OFF_DT;
    float* dbc = ws + OFF_DBC;
    float* yb  = ws + OFF_Y;
    float* ap  = ws + OFF_AP;
    float* he  = ws + OFF_HE;
    float* W1  = ws + OFF_W1;
    float* W2  = ws + OFF_W2;
    float* B3  = ws + OFF_B3;

    pack_weights<<<512, 256, 0, stream>>>(f_in_w, r_in_w, f_out_w, r_out_w,
                                          f_xproj, r_xproj, W1, W2, B3);

    // In-projection: [8192x256] @ [1024x256]^T -> xz [8192][1024]
    gemm_nt<<<dim3(1024 / 64, 8192 / 64), 256, 0, stream>>>(
        x, W1, xz, 8192, 1024, 256, 1 << 30, 0);

    // Conv + SiLU -> xc [2][8192][256]
    conv_silu_k<<<4096, 256, 0, stream>>>(xz, f_conv_w, f_conv_b, r_conv_w, r_conv_b, xcb);

    // x-projection: [16384x256] @ [48x256]^T (per-dir weights) -> dbc [16384][48]
    gemm_nt<<<dim3(1, 16384 / 64), 256, 0, stream>>>(
        xcb, B3, dbc, 16384, 48, 256, 8192, 48 * 256);

    // dt projection + softplus -> dt [2][8192][256]
    dt_kernel<<<16384, 256, 0, stream>>>(dbc, f_dt_w, f_dt_b, r_dt_w, r_dt_b, dtb);

    // Chunked selective scan
    scan1<<<4096, 256, 0, stream>>>(dtb, xcb, dbc, f_A_log, r_A_log, ap, he);
    scan2<<<128, 256, 0, stream>>>(ap, he);
    scan3<<<4096, 256, 0, stream>>>(dtb, xcb, dbc, xz, f_A_log, r_A_log, f_D, r_D, he, yb);

    // Out-projection: [8192x512] @ [256x512]^T -> out [8192][256]
    gemm_nt<<<dim3(256 / 64, 8192 / 64), 256, 0, stream>>>(
        yb, W2, (float*)d_out, 8192, 256, 512, 1 << 30, 0);
}

// Round 2
// 402.284 us; speedup vs baseline: 1.0786x; 1.0786x over previous
//
#include <hip/hip_runtime.h>
#include <math.h>

// Problem constants
constexpr int Bb = 4, Ll = 2048, Dd = 256, Nn = 16;
constexpr int ML = Bb * Ll;            // 8192 rows (b,l)
constexpr int NC = 32, LCH = Ll / NC;  // 32 chunks of 64

// Workspace layout (float offsets)
constexpr size_t OFF_XZ  = 0;                                   // [8192][1024] xz both dirs
constexpr size_t OFF_XC  = OFF_XZ  + (size_t)ML * 1024;         // [2][8192][256] conv+silu out
constexpr size_t OFF_DT  = OFF_XC  + (size_t)2 * ML * 256;      // [2][8192][256] dt (softplus applied)
constexpr size_t OFF_DBC = OFF_DT  + (size_t)2 * ML * 256;      // [16384][48] xproj out (dtraw|B|C)
constexpr size_t OFF_Y   = OFF_DBC + (size_t)2 * ML * 48;       // [8192][512] gated y (f|r)
constexpr size_t OFF_AP  = OFF_Y   + (size_t)ML * 512;          // [2][4][32][4096] chunk A-prod
constexpr size_t OFF_HE  = OFF_AP  + (size_t)2 * Bb * NC * Dd * Nn; // chunk h_end -> h_start
constexpr size_t OFF_W1  = OFF_HE  + (size_t)2 * Bb * NC * Dd * Nn; // [1024][256] packed in_w
constexpr size_t OFF_W2  = OFF_W1  + (size_t)1024 * 256;        // [256][512] packed out_w
constexpr size_t OFF_B3  = OFF_W2  + (size_t)256 * 512;         // [96][256] packed xproj_w

__global__ __launch_bounds__(256) void pack_weights(
    const float* __restrict__ f_in_w, const float* __restrict__ r_in_w,
    const float* __restrict__ f_out_w, const float* __restrict__ r_out_w,
    const float* __restrict__ f_xp, const float* __restrict__ r_xp,
    float* __restrict__ W1, float* __restrict__ W2, float* __restrict__ B3)
{
    int i = blockIdx.x * 256 + threadIdx.x;
    if (i < 131072) { W1[i] = f_in_w[i]; W1[131072 + i] = r_in_w[i]; }
    if (i < 65536) {
        int e = i >> 8, k = i & 255;
        W2[e * 512 + k]       = f_out_w[i];
        W2[e * 512 + 256 + k] = r_out_w[i];
    }
    if (i < 12288) { B3[i] = f_xp[i]; B3[12288 + i] = r_xp[i]; }
}

// Generic fp32 NT GEMM: C[M][N] = A[M][K] (row-major) * B[N][K]^T (row-major, K contiguous)
// For M-blocks beyond bSwitchM, B is offset by bAltOff (dir-dependent weights).
// Fragment map is STRIDED (m = ty + i*16, n = tx + j*16):
//   As reads: 4 addrs/wave stride 36 floats -> banks {0,4,8,12}, broadcast x16 -> conflict-free
//   Bs reads: 16 addrs stride 36 -> banks 4*tx%32 -> 2-way (free per m136)
__global__ __launch_bounds__(256) void gemm_nt(
    const float* __restrict__ A, const float* __restrict__ Bmat,
    float* __restrict__ C, int M, int N, int K, int bSwitchM, int bAltOff)
{
    constexpr int BM = 64, BN = 64, BK = 32, PK = 36;
    __shared__ float As[BM * PK];
    __shared__ float Bs[BN * PK];
    int m0 = blockIdx.y * BM, n0 = blockIdx.x * BN;
    const float* Bp = Bmat + ((m0 >= bSwitchM) ? bAltOff : 0);
    int t  = threadIdx.x;
    int tx = t & 15, ty = t >> 4;
    int lr  = t >> 3;          // 0..31
    int lc4 = (t & 7) * 4;     // 0,4,..,28
    float acc[4][4] = {};
    for (int k0 = 0; k0 < K; k0 += BK) {
        float4 av0 = *(const float4*)(A + (size_t)(m0 + lr)      * K + k0 + lc4);
        float4 av1 = *(const float4*)(A + (size_t)(m0 + lr + 32) * K + k0 + lc4);
        float4 bv0 = make_float4(0.f, 0.f, 0.f, 0.f), bv1 = bv0;
        if (n0 + lr      < N) bv0 = *(const float4*)(Bp + (size_t)(n0 + lr)      * K + k0 + lc4);
        if (n0 + lr + 32 < N) bv1 = *(const float4*)(Bp + (size_t)(n0 + lr + 32) * K + k0 + lc4);
        __syncthreads();
        *(float4*)(As + lr * PK + lc4)        = av0;
        *(float4*)(As + (lr + 32) * PK + lc4) = av1;
        *(float4*)(Bs + lr * PK + lc4)        = bv0;
        *(float4*)(Bs + (lr + 32) * PK + lc4) = bv1;
        __syncthreads();
        #pragma unroll
        for (int kq = 0; kq < BK / 4; ++kq) {
            float4 a4[4], b4[4];
            #pragma unroll
            for (int i = 0; i < 4; i++) a4[i] = *(const float4*)(As + (ty + i * 16) * PK + kq * 4);
            #pragma unroll
            for (int j = 0; j < 4; j++) b4[j] = *(const float4*)(Bs + (tx + j * 16) * PK + kq * 4);
            #pragma unroll
            for (int i = 0; i < 4; i++)
                #pragma unroll
                for (int j = 0; j < 4; j++)
                    acc[i][j] += a4[i].x * b4[j].x + a4[i].y * b4[j].y +
                                 a4[i].z * b4[j].z + a4[i].w * b4[j].w;
        }
    }
    #pragma unroll
    for (int i = 0; i < 4; i++) {
        int m = m0 + ty + i * 16;
        #pragma unroll
        for (int j = 0; j < 4; j++) {
            int n = n0 + tx + j * 16;
            if (n < N) C[(size_t)m * N + n] = acc[i][j];
        }
    }
}

// Depthwise conv width-2 + SiLU. dir 0 taps (l-1, l); dir 1 taps (l+1, l) in original order.
__global__ __launch_bounds__(256) void conv_silu_k(
    const float* __restrict__ xz,
    const float* __restrict__ fw, const float* __restrict__ fb,
    const float* __restrict__ rw, const float* __restrict__ rb,
    float* __restrict__ xc)
{
    int i = blockIdx.x * 256 + threadIdx.x;     // 0 .. 2*8192*64-1 (float4 granularity)
    int dir = i >> 19;
    int r   = i & 524287;
    int bl  = r >> 6;
    int l   = bl & 2047;
    int d4  = (r & 63) * 4;
    const float* cw = dir ? rw : fw;
    const float* cb = dir ? rb : fb;
    size_t rowc = (size_t)bl * 1024 + dir * 512 + d4;
    float4 cur = *(const float4*)(xz + rowc);
    float4 prv = make_float4(0.f, 0.f, 0.f, 0.f);
    if (dir == 0) { if (l > 0)      prv = *(const float4*)(xz + rowc - 1024); }
    else          { if (l < Ll - 1) prv = *(const float4*)(xz + rowc + 1024); }
    float pv[4] = {prv.x, prv.y, prv.z, prv.w};
    float cv[4] = {cur.x, cur.y, cur.z, cur.w};
    float out[4];
    #pragma unroll
    for (int j = 0; j < 4; j++) {
        float v = pv[j] * cw[(d4 + j) * 2] + cv[j] * cw[(d4 + j) * 2 + 1] + cb[d4 + j];
        out[j] = v / (1.f + __expf(-v));
    }
    *(float4*)(xc + (size_t)(dir * ML + bl) * 256 + d4) = make_float4(out[0], out[1], out[2], out[3]);
}

// dt[d] = softplus(sum_r dbc[r]*dt_w[d,r] + dt_b[d])
__global__ __launch_bounds__(256) void dt_kernel(
    const float* __restrict__ dbc,
    const float* __restrict__ fw, const float* __restrict__ fb,
    const float* __restrict__ rw, const float* __restrict__ rb,
    float* __restrict__ dt)
{
    int m = blockIdx.x;          // 0..16383 = dir*8192 + b*2048 + l
    int d = threadIdx.x;
    int dir = m >> 13;
    __shared__ float s[16];
    if (d < 16) s[d] = dbc[(size_t)m * 48 + d];
    __syncthreads();
    const float* w = (dir ? rw : fw) + d * 16;
    float acc = (dir ? rb : fb)[d];
    #pragma unroll
    for (int r = 0; r < 16; r++) acc += s[r] * w[r];
    float sp = (acc > 20.f) ? acc : log1pf(__expf(acc));
    dt[(size_t)m * 256 + d] = sp;
}

// Chunked scan pass 1: per-chunk local scan from h=0, record prod(dA) and local h_end.
__global__ __launch_bounds__(256) void scan1(
    const float* __restrict__ dt, const float* __restrict__ xc,
    const float* __restrict__ dbc,
    const float* __restrict__ fA, const float* __restrict__ rA,
    float* __restrict__ aprod, float* __restrict__ hend)
{
    int blk = blockIdx.x;                       // dir*2048 + b*512 + c*16 + dblk
    int dblk = blk & 15, c = (blk >> 4) & 31, b = (blk >> 9) & 3, dir = blk >> 11;
    int t = threadIdx.x;
    int d = dblk * 16 + (t >> 4), n = t & 15;   // n in low 4 lane bits (shuffle-reducible)
    float Ac = -__expf((dir ? rA : fA)[d * 16 + n]);
    float h = 0.f, ap = 1.f;
    int mbase = dir * ML + b * Ll;
    int s0 = c * LCH;
    for (int s = s0; s < s0 + LCH; ++s) {
        int l = dir ? (Ll - 1 - s) : s;
        int m = mbase + l;
        float dtv = dt[(size_t)m * Dd + d];
        float xcv = xc[(size_t)m * Dd + d];
        float bm  = dbc[(size_t)m * 48 + 16 + n];
        float da  = __expf(dtv * Ac);
        h  = fmaf(da, h, dtv * bm * xcv);
        ap *= da;
    }
    int idx = blk * 256 + t;
    aprod[idx] = ap;
    hend[idx]  = h;
}

// Pass 2: serial combine across chunks; overwrite hend with h_start per chunk.
__global__ __launch_bounds__(256) void scan2(
    const float* __restrict__ aprod, float* __restrict__ hend)
{
    int i = blockIdx.x * 256 + threadIdx.x;   // 0..32767 = dir*16384 + b*4096 + dn
    int dn = i & 4095, b = (i >> 12) & 3, dir = i >> 14;
    size_t base = ((size_t)(dir * 4 + b)) * NC * 4096 + dn;
    float h = 0.f;
    for (int c = 0; c < NC; c++) {
        size_t idx = base + (size_t)c * 4096;
        float ap = aprod[idx];
        float hl = hend[idx];
        hend[idx] = h;                         // h_start for this chunk
        h = fmaf(ap, h, hl);
    }
}

// Pass 3: replay chunk from h_start, emit y = (C.h + D*xc) * silu(z)
__global__ __launch_bounds__(256) void scan3(
    const float* __restrict__ dt, const float* __restrict__ xc,
    const float* __restrict__ dbc, const float* __restrict__ xz,
    const float* __restrict__ fA, const float* __restrict__ rA,
    const float* __restrict__ fDp, const float* __restrict__ rDp,
    const float* __restrict__ hstart, float* __restrict__ y)
{
    int blk = blockIdx.x;
    int dblk = blk & 15, c = (blk >> 4) & 31, b = (blk >> 9) & 3, dir = blk >> 11;
    int t = threadIdx.x;
    int d = dblk * 16 + (t >> 4), n = t & 15;
    float Ac = -__expf((dir ? rA : fA)[d * 16 + n]);
    float Dp = (dir ? rDp : fDp)[d];
    float h = hstart[blk * 256 + t];
    int mbase = dir * ML + b * Ll;
    int s0 = c * LCH;
    for (int s = s0; s < s0 + LCH; ++s) {
        int l = dir ? (Ll - 1 - s) : s;
        int m = mbase + l;
        int bl = b * Ll + l;
        float dtv = dt[(size_t)m * Dd + d];
        float xcv = xc[(size_t)m * Dd + d];
        float bm  = dbc[(size_t)m * 48 + 16 + n];
        float cm  = dbc[(size_t)m * 48 + 32 + n];
        float da  = __expf(dtv * Ac);
        h = fmaf(da, h, dtv * bm * xcv);
        float yp = h * cm;
        yp += __shfl_xor(yp, 1);
        yp += __shfl_xor(yp, 2);
        yp += __shfl_xor(yp, 4);
        yp += __shfl_xor(yp, 8);
        if (n == 0) {
            float z  = xz[(size_t)bl * 1024 + dir * 512 + 256 + d];
            float sz = z / (1.f + __expf(-z));
            y[(size_t)bl * 512 + dir * 256 + d] = (yp + Dp * xcv) * sz;
        }
    }
}

extern "C" void kernel_launch(void* const* d_in, const int* in_sizes, int n_in,
                              void* d_out, int out_size, void* d_ws, size_t ws_size,
                              hipStream_t stream)
{
    const float* x        = (const float*)d_in[0];
    const float* f_in_w   = (const float*)d_in[1];
    const float* f_conv_w = (const float*)d_in[2];
    const float* f_conv_b = (const float*)d_in[3];
    const float* f_xproj  = (const float*)d_in[4];
    const float* f_dt_w   = (const float*)d_in[5];
    const float* f_dt_b   = (const float*)d_in[6];
    const float* f_A_log  = (const float*)d_in[7];
    const float* f_D      = (const float*)d_in[8];
    const float* f_out_w  = (const float*)d_in[9];
    const float* r_in_w   = (const float*)d_in[10];
    const float* r_conv_w = (const float*)d_in[11];
    const float* r_conv_b = (const float*)d_in[12];
    const float* r_xproj  = (const float*)d_in[13];
    const float* r_dt_w   = (const float*)d_in[14];
    const float* r_dt_b   = (const float*)d_in[15];
    const float* r_A_log  = (const float*)d_in[16];
    const float* r_D      = (const float*)d_in[17];
    const float* r_out_w  = (const float*)d_in[18];

    float* ws  = (float*)d_ws;
    float* xz  = ws + OFF_XZ;
    float* xcb = ws + OFF_XC;
    float* dtb = ws + OFF_DT;
    float* dbc = ws + OFF_DBC;
    float* yb  = ws + OFF_Y;
    float* ap  = ws + OFF_AP;
    float* he  = ws + OFF_HE;
    float* W1  = ws + OFF_W1;
    float* W2  = ws + OFF_W2;
    float* B3  = ws + OFF_B3;

    pack_weights<<<512, 256, 0, stream>>>(f_in_w, r_in_w, f_out_w, r_out_w,
                                          f_xproj, r_xproj, W1, W2, B3);

    // In-projection: [8192x256] @ [1024x256]^T -> xz [8192][1024]
    gemm_nt<<<dim3(1024 / 64, 8192 / 64), 256, 0, stream>>>(
        x, W1, xz, 8192, 1024, 256, 1 << 30, 0);

    // Conv + SiLU -> xc [2][8192][256]
    conv_silu_k<<<4096, 256, 0, stream>>>(xz, f_conv_w, f_conv_b, r_conv_w, r_conv_b, xcb);

    // x-projection: [16384x256] @ [48x256]^T (per-dir weights) -> dbc [16384][48]
    gemm_nt<<<dim3(1, 16384 / 64), 256, 0, stream>>>(
        xcb, B3, dbc, 16384, 48, 256, 8192, 48 * 256);

    // dt projection + softplus -> dt [2][8192][256]
    dt_kernel<<<16384, 256, 0, stream>>>(dbc, f_dt_w, f_dt_b, r_dt_w, r_dt_b, dtb);

    // Chunked selective scan
    scan1<<<4096, 256, 0, stream>>>(dtb, xcb, dbc, f_A_log, r_A_log, ap, he);
    scan2<<<128, 256, 0, stream>>>(ap, he);
    scan3<<<4096, 256, 0, stream>>>(dtb, xcb, dbc, xz, f_A_log, r_A_log, f_D, r_D, he, yb);

    // Out-projection: [8192x512] @ [256x512]^T -> out [8192][256]
    gemm_nt<<<dim3(256 / 64, 8192 / 64), 256, 0, stream>>>(
        yb, W2, (float*)d_out, 8192, 256, 512, 1 << 30, 0);
}

// Round 3
// 371.247 us; speedup vs baseline: 1.1688x; 1.0836x over previous
//
#include <hip/hip_runtime.h>
#include <math.h>

// Problem constants
constexpr int Bb = 4, Ll = 2048, Dd = 256, Nn = 16;
constexpr int ML = Bb * Ll;            // 8192 rows (b,l)
constexpr int NC = 32, LCH = Ll / NC;  // 32 chunks of 64

// Workspace layout (float offsets)
constexpr size_t OFF_XZ  = 0;                                   // [8192][1024] xz both dirs
constexpr size_t OFF_XC  = OFF_XZ  + (size_t)ML * 1024;         // [2][8192][256] conv+silu out
constexpr size_t OFF_DT  = OFF_XC  + (size_t)2 * ML * 256;      // [2][8192][256] dt (softplus applied)
constexpr size_t OFF_DBC = OFF_DT  + (size_t)2 * ML * 256;      // [16384][48] xproj out (dtraw|B|C)
constexpr size_t OFF_Y   = OFF_DBC + (size_t)2 * ML * 48;       // [8192][512] gated y (f|r)
constexpr size_t OFF_AP  = OFF_Y   + (size_t)ML * 512;          // [2][4][32][4096] chunk A-prod
constexpr size_t OFF_HE  = OFF_AP  + (size_t)2 * Bb * NC * Dd * Nn; // chunk h_end -> h_start
constexpr size_t OFF_W1  = OFF_HE  + (size_t)2 * Bb * NC * Dd * Nn; // [1024][256] packed in_w
constexpr size_t OFF_W2  = OFF_W1  + (size_t)1024 * 256;        // [256][512] packed out_w
constexpr size_t OFF_B3  = OFF_W2  + (size_t)256 * 512;         // [96][256] packed xproj_w

__global__ __launch_bounds__(256) void pack_weights(
    const float* __restrict__ f_in_w, const float* __restrict__ r_in_w,
    const float* __restrict__ f_out_w, const float* __restrict__ r_out_w,
    const float* __restrict__ f_xp, const float* __restrict__ r_xp,
    float* __restrict__ W1, float* __restrict__ W2, float* __restrict__ B3)
{
    int i = blockIdx.x * 256 + threadIdx.x;
    if (i < 131072) { W1[i] = f_in_w[i]; W1[131072 + i] = r_in_w[i]; }
    if (i < 65536) {
        int e = i >> 8, k = i & 255;
        W2[e * 512 + k]       = f_out_w[i];
        W2[e * 512 + 256 + k] = r_out_w[i];
    }
    if (i < 12288) { B3[i] = f_xp[i]; B3[12288 + i] = r_xp[i]; }
}

// Generic fp32 NT GEMM: C[M][N] = A[M][K] (row-major) * B[N][K]^T (row-major, K contiguous)
// Strided fragment map (m = ty + i*16, n = tx + j*16): As conflict-free, Bs 2-way (free).
__global__ __launch_bounds__(256) void gemm_nt(
    const float* __restrict__ A, const float* __restrict__ Bmat,
    float* __restrict__ C, int M, int N, int K, int bSwitchM, int bAltOff)
{
    constexpr int BM = 64, BN = 64, BK = 32, PK = 36;
    __shared__ float As[BM * PK];
    __shared__ float Bs[BN * PK];
    int m0 = blockIdx.y * BM, n0 = blockIdx.x * BN;
    const float* Bp = Bmat + ((m0 >= bSwitchM) ? bAltOff : 0);
    int t  = threadIdx.x;
    int tx = t & 15, ty = t >> 4;
    int lr  = t >> 3;          // 0..31
    int lc4 = (t & 7) * 4;     // 0,4,..,28
    float acc[4][4] = {};
    for (int k0 = 0; k0 < K; k0 += BK) {
        float4 av0 = *(const float4*)(A + (size_t)(m0 + lr)      * K + k0 + lc4);
        float4 av1 = *(const float4*)(A + (size_t)(m0 + lr + 32) * K + k0 + lc4);
        float4 bv0 = make_float4(0.f, 0.f, 0.f, 0.f), bv1 = bv0;
        if (n0 + lr      < N) bv0 = *(const float4*)(Bp + (size_t)(n0 + lr)      * K + k0 + lc4);
        if (n0 + lr + 32 < N) bv1 = *(const float4*)(Bp + (size_t)(n0 + lr + 32) * K + k0 + lc4);
        __syncthreads();
        *(float4*)(As + lr * PK + lc4)        = av0;
        *(float4*)(As + (lr + 32) * PK + lc4) = av1;
        *(float4*)(Bs + lr * PK + lc4)        = bv0;
        *(float4*)(Bs + (lr + 32) * PK + lc4) = bv1;
        __syncthreads();
        #pragma unroll
        for (int kq = 0; kq < BK / 4; ++kq) {
            float4 a4[4], b4[4];
            #pragma unroll
            for (int i = 0; i < 4; i++) a4[i] = *(const float4*)(As + (ty + i * 16) * PK + kq * 4);
            #pragma unroll
            for (int j = 0; j < 4; j++) b4[j] = *(const float4*)(Bs + (tx + j * 16) * PK + kq * 4);
            #pragma unroll
            for (int i = 0; i < 4; i++)
                #pragma unroll
                for (int j = 0; j < 4; j++)
                    acc[i][j] += a4[i].x * b4[j].x + a4[i].y * b4[j].y +
                                 a4[i].z * b4[j].z + a4[i].w * b4[j].w;
        }
    }
    #pragma unroll
    for (int i = 0; i < 4; i++) {
        int m = m0 + ty + i * 16;
        #pragma unroll
        for (int j = 0; j < 4; j++) {
            int n = n0 + tx + j * 16;
            if (n < N) C[(size_t)m * N + n] = acc[i][j];
        }
    }
}

// Depthwise conv width-2 + SiLU. dir 0 taps (l-1, l); dir 1 taps (l+1, l) in original order.
__global__ __launch_bounds__(256) void conv_silu_k(
    const float* __restrict__ xz,
    const float* __restrict__ fw, const float* __restrict__ fb,
    const float* __restrict__ rw, const float* __restrict__ rb,
    float* __restrict__ xc)
{
    int i = blockIdx.x * 256 + threadIdx.x;     // 0 .. 2*8192*64-1 (float4 granularity)
    int dir = i >> 19;
    int r   = i & 524287;
    int bl  = r >> 6;
    int l   = bl & 2047;
    int d4  = (r & 63) * 4;
    const float* cw = dir ? rw : fw;
    const float* cb = dir ? rb : fb;
    size_t rowc = (size_t)bl * 1024 + dir * 512 + d4;
    float4 cur = *(const float4*)(xz + rowc);
    float4 prv = make_float4(0.f, 0.f, 0.f, 0.f);
    if (dir == 0) { if (l > 0)      prv = *(const float4*)(xz + rowc - 1024); }
    else          { if (l < Ll - 1) prv = *(const float4*)(xz + rowc + 1024); }
    float pv[4] = {prv.x, prv.y, prv.z, prv.w};
    float cv[4] = {cur.x, cur.y, cur.z, cur.w};
    float out[4];
    #pragma unroll
    for (int j = 0; j < 4; j++) {
        float v = pv[j] * cw[(d4 + j) * 2] + cv[j] * cw[(d4 + j) * 2 + 1] + cb[d4 + j];
        out[j] = v / (1.f + __expf(-v));
    }
    *(float4*)(xc + (size_t)(dir * ML + bl) * 256 + d4) = make_float4(out[0], out[1], out[2], out[3]);
}

// dt[d] = softplus(sum_r dbc[r]*dt_w[d,r] + dt_b[d])
__global__ __launch_bounds__(256) void dt_kernel(
    const float* __restrict__ dbc,
    const float* __restrict__ fw, const float* __restrict__ fb,
    const float* __restrict__ rw, const float* __restrict__ rb,
    float* __restrict__ dt)
{
    int m = blockIdx.x;          // 0..16383 = dir*8192 + b*2048 + l
    int d = threadIdx.x;
    int dir = m >> 13;
    __shared__ float s[16];
    if (d < 16) s[d] = dbc[(size_t)m * 48 + d];
    __syncthreads();
    const float* w = (dir ? rw : fw) + d * 16;
    float acc = (dir ? rb : fb)[d];
    #pragma unroll
    for (int r = 0; r < 16; r++) acc += s[r] * w[r];
    float sp = (acc > 20.f) ? acc : log1pf(__expf(acc));
    dt[(size_t)m * 256 + d] = sp;
}

// Chunked scan pass 1, direction-templated, unroll-8 with batched independent loads.
// Per-chunk local scan from h=0, record prod(dA) and local h_end.
template<int SGN>
__global__ __launch_bounds__(256) void scan1_t(
    const float* __restrict__ dt, const float* __restrict__ xc,
    const float* __restrict__ dbc, const float* __restrict__ Alog,
    float* __restrict__ aprod, float* __restrict__ hend, int mdir)
{
    int blk = blockIdx.x;                       // b*512 + c*16 + dblk  (one dir)
    int dblk = blk & 15, c = (blk >> 4) & 31, b = blk >> 9;
    int t = threadIdx.x;
    int d = dblk * 16 + (t >> 4), n = t & 15;
    float Ac = -__expf(Alog[d * 16 + n]);
    int l0 = (SGN > 0) ? c * LCH : (Ll - 1 - c * LCH);
    size_t m0 = (size_t)(mdir + b * Ll + l0);
    const float* pdt = dt + m0 * Dd + d;
    const float* pxc = xc + m0 * Dd + d;
    const float* pbm = dbc + m0 * 48 + 16 + n;
    float h = 0.f, ap = 1.f;
    for (int u = 0; u < LCH / 8; ++u) {
        float vdt[8], vxc[8], vbm[8];
        #pragma unroll
        for (int j = 0; j < 8; ++j) {
            ptrdiff_t o = (ptrdiff_t)SGN * j;
            vdt[j] = pdt[o * Dd];
            vxc[j] = pxc[o * Dd];
            vbm[j] = pbm[o * 48];
        }
        #pragma unroll
        for (int j = 0; j < 8; ++j) {
            float da = __expf(vdt[j] * Ac);
            h  = fmaf(da, h, vdt[j] * vbm[j] * vxc[j]);
            ap *= da;
        }
        pdt += (ptrdiff_t)SGN * 8 * Dd;
        pxc += (ptrdiff_t)SGN * 8 * Dd;
        pbm += (ptrdiff_t)SGN * 8 * 48;
    }
    int idx = blk * 256 + t;
    aprod[idx] = ap;
    hend[idx]  = h;
}

// Pass 2: serial combine across chunks; overwrite hend with h_start per chunk.
__global__ __launch_bounds__(256) void scan2(
    const float* __restrict__ aprod, float* __restrict__ hend)
{
    int i = blockIdx.x * 256 + threadIdx.x;   // 0..32767 = dir*16384 + b*4096 + dn
    int dn = i & 4095, b = (i >> 12) & 3, dir = i >> 14;
    size_t base = ((size_t)(dir * 4 + b)) * NC * 4096 + dn;
    float h = 0.f;
    for (int c = 0; c < NC; c++) {
        size_t idx = base + (size_t)c * 4096;
        float ap = aprod[idx];
        float hl = hend[idx];
        hend[idx] = h;                         // h_start for this chunk
        h = fmaf(ap, h, hl);
    }
}

// Pass 3, direction-templated, unroll-8: replay chunk from h_start,
// emit y = (C.h + D*xc) * silu(z)
template<int SGN>
__global__ __launch_bounds__(256) void scan3_t(
    const float* __restrict__ dt, const float* __restrict__ xc,
    const float* __restrict__ dbc, const float* __restrict__ xz,
    const float* __restrict__ Alog, const float* __restrict__ Dparm,
    const float* __restrict__ hstart, float* __restrict__ y,
    int mdir, int zoff, int yoff)
{
    int blk = blockIdx.x;
    int dblk = blk & 15, c = (blk >> 4) & 31, b = blk >> 9;
    int t = threadIdx.x;
    int d = dblk * 16 + (t >> 4), n = t & 15;
    float Ac = -__expf(Alog[d * 16 + n]);
    float Dp = Dparm[d];
    float h = hstart[blk * 256 + t];
    int l0 = (SGN > 0) ? c * LCH : (Ll - 1 - c * LCH);
    size_t bl0 = (size_t)(b * Ll + l0);
    size_t m0 = (size_t)mdir + bl0;
    const float* pdt = dt + m0 * Dd + d;
    const float* pxc = xc + m0 * Dd + d;
    const float* pbm = dbc + m0 * 48 + 16 + n;
    const float* pcm = dbc + m0 * 48 + 32 + n;
    const float* pz  = xz + bl0 * 1024 + zoff + d;
    float*       py  = y  + bl0 * 512  + yoff + d;
    for (int u = 0; u < LCH / 8; ++u) {
        float vdt[8], vxc[8], vbm[8], vcm[8], vz[8];
        #pragma unroll
        for (int j = 0; j < 8; ++j) {
            ptrdiff_t o = (ptrdiff_t)SGN * j;
            vdt[j] = pdt[o * Dd];
            vxc[j] = pxc[o * Dd];
            vbm[j] = pbm[o * 48];
            vcm[j] = pcm[o * 48];
            vz[j]  = pz[o * 1024];
        }
        #pragma unroll
        for (int j = 0; j < 8; ++j) {
            float da = __expf(vdt[j] * Ac);
            h = fmaf(da, h, vdt[j] * vbm[j] * vxc[j]);
            float yp = h * vcm[j];
            yp += __shfl_xor(yp, 1);
            yp += __shfl_xor(yp, 2);
            yp += __shfl_xor(yp, 4);
            yp += __shfl_xor(yp, 8);
            float zv = vz[j];
            float sz = zv / (1.f + __expf(-zv));
            float out = (yp + Dp * vxc[j]) * sz;
            if (n == 0) py[(ptrdiff_t)SGN * j * 512] = out;
        }
        pdt += (ptrdiff_t)SGN * 8 * Dd;
        pxc += (ptrdiff_t)SGN * 8 * Dd;
        pbm += (ptrdiff_t)SGN * 8 * 48;
        pcm += (ptrdiff_t)SGN * 8 * 48;
        pz  += (ptrdiff_t)SGN * 8 * 1024;
        py  += (ptrdiff_t)SGN * 8 * 512;
    }
}

extern "C" void kernel_launch(void* const* d_in, const int* in_sizes, int n_in,
                              void* d_out, int out_size, void* d_ws, size_t ws_size,
                              hipStream_t stream)
{
    const float* x        = (const float*)d_in[0];
    const float* f_in_w   = (const float*)d_in[1];
    const float* f_conv_w = (const float*)d_in[2];
    const float* f_conv_b = (const float*)d_in[3];
    const float* f_xproj  = (const float*)d_in[4];
    const float* f_dt_w   = (const float*)d_in[5];
    const float* f_dt_b   = (const float*)d_in[6];
    const float* f_A_log  = (const float*)d_in[7];
    const float* f_D      = (const float*)d_in[8];
    const float* f_out_w  = (const float*)d_in[9];
    const float* r_in_w   = (const float*)d_in[10];
    const float* r_conv_w = (const float*)d_in[11];
    const float* r_conv_b = (const float*)d_in[12];
    const float* r_xproj  = (const float*)d_in[13];
    const float* r_dt_w   = (const float*)d_in[14];
    const float* r_dt_b   = (const float*)d_in[15];
    const float* r_A_log  = (const float*)d_in[16];
    const float* r_D      = (const float*)d_in[17];
    const float* r_out_w  = (const float*)d_in[18];

    float* ws  = (float*)d_ws;
    float* xz  = ws + OFF_XZ;
    float* xcb = ws + OFF_XC;
    float* dtb = ws + OFF_DT;
    float* dbc = ws + OFF_DBC;
    float* yb  = ws + OFF_Y;
    float* ap  = ws + OFF_AP;
    float* he  = ws + OFF_HE;
    float* W1  = ws + OFF_W1;
    float* W2  = ws + OFF_W2;
    float* B3  = ws + OFF_B3;

    pack_weights<<<512, 256, 0, stream>>>(f_in_w, r_in_w, f_out_w, r_out_w,
                                          f_xproj, r_xproj, W1, W2, B3);

    // In-projection: [8192x256] @ [1024x256]^T -> xz [8192][1024]
    gemm_nt<<<dim3(1024 / 64, 8192 / 64), 256, 0, stream>>>(
        x, W1, xz, 8192, 1024, 256, 1 << 30, 0);

    // Conv + SiLU -> xc [2][8192][256]
    conv_silu_k<<<4096, 256, 0, stream>>>(xz, f_conv_w, f_conv_b, r_conv_w, r_conv_b, xcb);

    // x-projection: [16384x256] @ [48x256]^T (per-dir weights) -> dbc [16384][48]
    gemm_nt<<<dim3(1, 16384 / 64), 256, 0, stream>>>(
        xcb, B3, dbc, 16384, 48, 256, 8192, 48 * 256);

    // dt projection + softplus -> dt [2][8192][256]
    dt_kernel<<<16384, 256, 0, stream>>>(dbc, f_dt_w, f_dt_b, r_dt_w, r_dt_b, dtb);

    // Chunked selective scan (dir-templated, 2048 blocks per dir)
    scan1_t< 1><<<2048, 256, 0, stream>>>(dtb, xcb, dbc, f_A_log, ap, he, 0);
    scan1_t<-1><<<2048, 256, 0, stream>>>(dtb, xcb, dbc, r_A_log,
                                          ap + 2048 * 256, he + 2048 * 256, ML);
    scan2<<<128, 256, 0, stream>>>(ap, he);
    scan3_t< 1><<<2048, 256, 0, stream>>>(dtb, xcb, dbc, xz, f_A_log, f_D,
                                          he, yb, 0, 256, 0);
    scan3_t<-1><<<2048, 256, 0, stream>>>(dtb, xcb, dbc, xz, r_A_log, r_D,
                                          he + 2048 * 256, yb, ML, 512 + 256, 256);

    // Out-projection: [8192x512] @ [256x512]^T -> out [8192][256]
    gemm_nt<<<dim3(256 / 64, 8192 / 64), 256, 0, stream>>>(
        yb, W2, (float*)d_out, 8192, 256, 512, 1 << 30, 0);
}

// Round 5
// 303.859 us; speedup vs baseline: 1.4280x; 1.2218x over previous
//
#include <hip/hip_runtime.h>
#include <math.h>

typedef __bf16 bf16_t;
typedef bf16_t bf16x8 __attribute__((ext_vector_type(8)));
typedef float f32x4 __attribute__((ext_vector_type(4)));

// Problem constants
constexpr int Bb = 4, Ll = 2048, Dd = 256, Nn = 16;
constexpr int ML = Bb * Ll;            // 8192 rows (b,l)
constexpr int NC = 32, LCH = Ll / NC;  // 32 chunks of 64

// Workspace layout (float offsets)
constexpr size_t OFF_XZ  = 0;                                   // [8192][1024] xz both dirs
constexpr size_t OFF_XC  = OFF_XZ  + (size_t)ML * 1024;         // [2][8192][256] conv+silu out
constexpr size_t OFF_DT  = OFF_XC  + (size_t)2 * ML * 256;      // [2][8192][256] dt
constexpr size_t OFF_DBC = OFF_DT  + (size_t)2 * ML * 256;      // [16384][48] xproj out
constexpr size_t OFF_Y   = OFF_DBC + (size_t)2 * ML * 48;       // [8192][512] gated y (f|r)
constexpr size_t OFF_AP  = OFF_Y   + (size_t)ML * 512;          // 1M floats chunk A-prod
constexpr size_t OFF_HE  = OFF_AP  + (size_t)2 * Bb * NC * Dd * Nn; // 1M floats
constexpr size_t OFF_W1  = OFF_HE  + (size_t)2 * Bb * NC * Dd * Nn; // [1024][256] packed in_w
constexpr size_t OFF_W2  = OFF_W1  + (size_t)1024 * 256;        // [256][512] packed out_w
constexpr size_t OFF_B3  = OFF_W2  + (size_t)256 * 512;         // [96][256] packed xproj_w
// bf16 plane aliases (all in dead regions at their time of use):
//   XH @ AP, XL @ HE          (consumed by in-proj, then scans overwrite)
//   W1H/W1L @ Y               (consumed by in-proj, scan3 overwrites later)
//   YH/YL @ XZ                (written after scan3; xz dead then)
//   W2H/W2L @ AP              (written after scan2; ap dead then)

__global__ __launch_bounds__(256) void pack_weights(
    const float* __restrict__ f_in_w, const float* __restrict__ r_in_w,
    const float* __restrict__ f_out_w, const float* __restrict__ r_out_w,
    const float* __restrict__ f_xp, const float* __restrict__ r_xp,
    float* __restrict__ W1, float* __restrict__ W2, float* __restrict__ B3)
{
    int i = blockIdx.x * 256 + threadIdx.x;
    if (i < 131072) { W1[i] = f_in_w[i]; W1[131072 + i] = r_in_w[i]; }
    if (i < 65536) {
        int e = i >> 8, k = i & 255;
        W2[e * 512 + k]       = f_out_w[i];
        W2[e * 512 + 256 + k] = r_out_w[i];
    }
    if (i < 12288) { B3[i] = f_xp[i]; B3[12288 + i] = r_xp[i]; }
}

// fp32 [M][K] row-major -> hi/lo bf16 planes in MFMA-blocked layout [m>>7][k>>3][m&127][k&7].
// One thread per 8-elem k-group; gid = (mb*K8 + kbg)*128 + r  (writes coalesced).
__global__ __launch_bounds__(256) void cvt_split(
    const float* __restrict__ src, bf16_t* __restrict__ dh, bf16_t* __restrict__ dl, int lgK8)
{
    int gid = blockIdx.x * 256 + threadIdx.x;
    int r = gid & 127;
    int tmp = gid >> 7;
    int kbg = tmp & ((1 << lgK8) - 1);
    int mb  = tmp >> lgK8;
    const float* p = src + ((size_t)(mb * 128 + r) << (lgK8 + 3)) + kbg * 8;
    float4 u0 = ((const float4*)p)[0];
    float4 u1 = ((const float4*)p)[1];
    float v[8] = {u0.x, u0.y, u0.z, u0.w, u1.x, u1.y, u1.z, u1.w};
    bf16x8 h8, l8;
    #pragma unroll
    for (int j = 0; j < 8; ++j) {
        bf16_t hb = (bf16_t)v[j];
        float  hf = (float)hb;
        bf16_t lb = (bf16_t)(v[j] - hf);
        h8[j] = hb;
        l8[j] = lb;
    }
    ((bf16x8*)dh)[gid] = h8;
    ((bf16x8*)dl)[gid] = l8;
}

// Split-bf16 MFMA GEMM: C[M][N] = (Ah+Al)[M][K] * (Bh+Bl)[N][K]^T (3-term, fp32 acc).
// A/B pre-converted to blocked layout by cvt_split (always 128-row blocks).
// Tile BM x 128, K-step 32, 256 threads = 4 waves (2x2), wave tile (FI*16) x 64.
// AHALF: set when BM=64 but A is stored 128-row-blocked — each tile consumes
//        the (mb&1) 64-row half of A-block mb>>1; each 512-elem chunk is then
//        one kbg's 64 rows (kbg stride in source = 128*8 elems).
template<int FI, bool AHALF>   // FI = BM/32 : 4 -> BM=128, 2 -> BM=64
__global__ __launch_bounds__(256) void gemm_mfma(
    const bf16_t* __restrict__ Ahg, const bf16_t* __restrict__ Alg,
    const bf16_t* __restrict__ Bhg, const bf16_t* __restrict__ Blg,
    float* __restrict__ C, int K, int N)
{
    constexpr int BM = FI * 32;
    constexpr int AE = 32 * BM;        // elems per A plane per K-step
    constexpr int BE = 32 * 128;       // elems per B plane per K-step
    constexpr int CA = AE / 512;       // 1-KB chunks per A plane
    constexpr int CB = BE / 512;       // 8
    constexpr int NCH = 2 * CA + 2 * CB;
    constexpr int QC = NCH / 4;        // chunks per wave
    __shared__ alignas(16) bf16_t sAh[AE], sAl[AE], sBh[BE], sBl[BE];
    const int t = threadIdx.x, w = t >> 6, l = t & 63;
    const int mb = blockIdx.y, nb = blockIdx.x;
    const int K8 = K >> 3;
    const int wm = w >> 1, wn = w & 1;
    const int lr = l & 15, kb = l >> 4;
    const size_t aoff = AHALF ? ((size_t)(mb >> 1) * K8 * (128 * 8) + (size_t)(mb & 1) * 512)
                              : (size_t)mb * K8 * (BM * 8);
    const size_t boff = (size_t)nb * K8 * (128 * 8);

    auto gsrc = [&](int c, int ks) -> const bf16_t* {
        if (c < 2 * CA) {
            const bf16_t* base = (c < CA) ? Ahg : Alg;
            int ca = (c < CA) ? c : c - CA;
            if (AHALF) return base + aoff + (size_t)(ks * CA + ca) * (128 * 8);
            else       return base + aoff + (size_t)ks * AE + ca * 512;
        } else {
            const bf16_t* base = (c < 2 * CA + CB) ? Bhg : Blg;
            int cbn = (c < 2 * CA + CB) ? (c - 2 * CA) : (c - 2 * CA - CB);
            return base + boff + (size_t)ks * BE + cbn * 512;
        }
    };
    auto sdst = [&](int c) -> bf16_t* {
        if (c < CA)              return sAh + c * 512;
        else if (c < 2 * CA)     return sAl + (c - CA) * 512;
        else if (c < 2 * CA + CB) return sBh + (c - 2 * CA) * 512;
        else                     return sBl + (c - 2 * CA - CB) * 512;
    };

    f32x4 acc[FI][4] = {};
    bf16x8 vst[QC];
    #pragma unroll
    for (int q = 0; q < QC; ++q)
        vst[q] = *(const bf16x8*)(gsrc(w + q * 4, 0) + l * 8);

    const int KS = K / 32;
    for (int ks = 0;; ++ks) {
        __syncthreads();
        #pragma unroll
        for (int q = 0; q < QC; ++q)
            *(bf16x8*)(sdst(w + q * 4) + l * 8) = vst[q];
        __syncthreads();
        if (ks + 1 < KS) {
            #pragma unroll
            for (int q = 0; q < QC; ++q)
                vst[q] = *(const bf16x8*)(gsrc(w + q * 4, ks + 1) + l * 8);
        }
        bf16x8 ah[FI], al[FI], bh[4], bl[4];
        #pragma unroll
        for (int i = 0; i < FI; ++i) {
            int row = wm * (FI * 16) + i * 16 + lr;
            ah[i] = *(const bf16x8*)(sAh + (kb * BM + row) * 8);
            al[i] = *(const bf16x8*)(sAl + (kb * BM + row) * 8);
        }
        #pragma unroll
        for (int j = 0; j < 4; ++j) {
            int col = wn * 64 + j * 16 + lr;
            bh[j] = *(const bf16x8*)(sBh + (kb * 128 + col) * 8);
            bl[j] = *(const bf16x8*)(sBl + (kb * 128 + col) * 8);
        }
        #pragma unroll
        for (int i = 0; i < FI; ++i)
            #pragma unroll
            for (int j = 0; j < 4; ++j) {
                acc[i][j] = __builtin_amdgcn_mfma_f32_16x16x32_bf16(ah[i], bh[j], acc[i][j], 0, 0, 0);
                acc[i][j] = __builtin_amdgcn_mfma_f32_16x16x32_bf16(ah[i], bl[j], acc[i][j], 0, 0, 0);
                acc[i][j] = __builtin_amdgcn_mfma_f32_16x16x32_bf16(al[i], bh[j], acc[i][j], 0, 0, 0);
            }
        if (ks + 1 == KS) break;
    }
    // Epilogue: D col = lane&15, row = (lane>>4)*4 + reg  (m89-verified)
    #pragma unroll
    for (int i = 0; i < FI; ++i)
        #pragma unroll
        for (int p = 0; p < 4; ++p) {
            int m = mb * BM + wm * (FI * 16) + i * 16 + kb * 4 + p;
            float* cp = C + (size_t)m * N + nb * 128 + wn * 64 + lr;
            #pragma unroll
            for (int j = 0; j < 4; ++j) cp[j * 16] = acc[i][j][p];
        }
}

// Generic fp32 NT GEMM (kept for the small xproj: N=48).
__global__ __launch_bounds__(256) void gemm_nt(
    const float* __restrict__ A, const float* __restrict__ Bmat,
    float* __restrict__ C, int M, int N, int K, int bSwitchM, int bAltOff)
{
    constexpr int BM = 64, BN = 64, BK = 32, PK = 36;
    __shared__ float As[BM * PK];
    __shared__ float Bs[BN * PK];
    int m0 = blockIdx.y * BM, n0 = blockIdx.x * BN;
    const float* Bp = Bmat + ((m0 >= bSwitchM) ? bAltOff : 0);
    int t  = threadIdx.x;
    int tx = t & 15, ty = t >> 4;
    int lr  = t >> 3;
    int lc4 = (t & 7) * 4;
    float acc[4][4] = {};
    for (int k0 = 0; k0 < K; k0 += BK) {
        float4 av0 = *(const float4*)(A + (size_t)(m0 + lr)      * K + k0 + lc4);
        float4 av1 = *(const float4*)(A + (size_t)(m0 + lr + 32) * K + k0 + lc4);
        float4 bv0 = make_float4(0.f, 0.f, 0.f, 0.f), bv1 = bv0;
        if (n0 + lr      < N) bv0 = *(const float4*)(Bp + (size_t)(n0 + lr)      * K + k0 + lc4);
        if (n0 + lr + 32 < N) bv1 = *(const float4*)(Bp + (size_t)(n0 + lr + 32) * K + k0 + lc4);
        __syncthreads();
        *(float4*)(As + lr * PK + lc4)        = av0;
        *(float4*)(As + (lr + 32) * PK + lc4) = av1;
        *(float4*)(Bs + lr * PK + lc4)        = bv0;
        *(float4*)(Bs + (lr + 32) * PK + lc4) = bv1;
        __syncthreads();
        #pragma unroll
        for (int kq = 0; kq < BK / 4; ++kq) {
            float4 a4[4], b4[4];
            #pragma unroll
            for (int i = 0; i < 4; i++) a4[i] = *(const float4*)(As + (ty + i * 16) * PK + kq * 4);
            #pragma unroll
            for (int j = 0; j < 4; j++) b4[j] = *(const float4*)(Bs + (tx + j * 16) * PK + kq * 4);
            #pragma unroll
            for (int i = 0; i < 4; i++)
                #pragma unroll
                for (int j = 0; j < 4; j++)
                    acc[i][j] += a4[i].x * b4[j].x + a4[i].y * b4[j].y +
                                 a4[i].z * b4[j].z + a4[i].w * b4[j].w;
        }
    }
    #pragma unroll
    for (int i = 0; i < 4; i++) {
        int m = m0 + ty + i * 16;
        #pragma unroll
        for (int j = 0; j < 4; j++) {
            int n = n0 + tx + j * 16;
            if (n < N) C[(size_t)m * N + n] = acc[i][j];
        }
    }
}

// Depthwise conv width-2 + SiLU. dir 0 taps (l-1, l); dir 1 taps (l+1, l).
__global__ __launch_bounds__(256) void conv_silu_k(
    const float* __restrict__ xz,
    const float* __restrict__ fw, const float* __restrict__ fb,
    const float* __restrict__ rw, const float* __restrict__ rb,
    float* __restrict__ xc)
{
    int i = blockIdx.x * 256 + threadIdx.x;
    int dir = i >> 19;
    int r   = i & 524287;
    int bl  = r >> 6;
    int l   = bl & 2047;
    int d4  = (r & 63) * 4;
    const float* cw = dir ? rw : fw;
    const float* cb = dir ? rb : fb;
    size_t rowc = (size_t)bl * 1024 + dir * 512 + d4;
    float4 cur = *(const float4*)(xz + rowc);
    float4 prv = make_float4(0.f, 0.f, 0.f, 0.f);
    if (dir == 0) { if (l > 0)      prv = *(const float4*)(xz + rowc - 1024); }
    else          { if (l < Ll - 1) prv = *(const float4*)(xz + rowc + 1024); }
    float pv[4] = {prv.x, prv.y, prv.z, prv.w};
    float cv[4] = {cur.x, cur.y, cur.z, cur.w};
    float out[4];
    #pragma unroll
    for (int j = 0; j < 4; j++) {
        float v = pv[j] * cw[(d4 + j) * 2] + cv[j] * cw[(d4 + j) * 2 + 1] + cb[d4 + j];
        out[j] = v / (1.f + __expf(-v));
    }
    *(float4*)(xc + (size_t)(dir * ML + bl) * 256 + d4) = make_float4(out[0], out[1], out[2], out[3]);
}

// dt[d] = softplus(sum_r dbc[r]*dt_w[d,r] + dt_b[d])
__global__ __launch_bounds__(256) void dt_kernel(
    const float* __restrict__ dbc,
    const float* __restrict__ fw, const float* __restrict__ fb,
    const float* __restrict__ rw, const float* __restrict__ rb,
    float* __restrict__ dt)
{
    int m = blockIdx.x;
    int d = threadIdx.x;
    int dir = m >> 13;
    __shared__ float s[16];
    if (d < 16) s[d] = dbc[(size_t)m * 48 + d];
    __syncthreads();
    const float* w = (dir ? rw : fw) + d * 16;
    float acc = (dir ? rb : fb)[d];
    #pragma unroll
    for (int r = 0; r < 16; r++) acc += s[r] * w[r];
    float sp = (acc > 20.f) ? acc : log1pf(__expf(acc));
    dt[(size_t)m * 256 + d] = sp;
}

// Chunked scan pass 1, direction-templated, unroll-8 batched loads.
template<int SGN>
__global__ __launch_bounds__(256) void scan1_t(
    const float* __restrict__ dt, const float* __restrict__ xc,
    const float* __restrict__ dbc, const float* __restrict__ Alog,
    float* __restrict__ aprod, float* __restrict__ hend, int mdir)
{
    int blk = blockIdx.x;
    int dblk = blk & 15, c = (blk >> 4) & 31, b = blk >> 9;
    int t = threadIdx.x;
    int d = dblk * 16 + (t >> 4), n = t & 15;
    float Ac = -__expf(Alog[d * 16 + n]);
    int l0 = (SGN > 0) ? c * LCH : (Ll - 1 - c * LCH);
    size_t m0 = (size_t)(mdir + b * Ll + l0);
    const float* pdt = dt + m0 * Dd + d;
    const float* pxc = xc + m0 * Dd + d;
    const float* pbm = dbc + m0 * 48 + 16 + n;
    float h = 0.f, ap = 1.f;
    for (int u = 0; u < LCH / 8; ++u) {
        float vdt[8], vxc[8], vbm[8];
        #pragma unroll
        for (int j = 0; j < 8; ++j) {
            ptrdiff_t o = (ptrdiff_t)SGN * j;
            vdt[j] = pdt[o * Dd];
            vxc[j] = pxc[o * Dd];
            vbm[j] = pbm[o * 48];
        }
        #pragma unroll
        for (int j = 0; j < 8; ++j) {
            float da = __expf(vdt[j] * Ac);
            h  = fmaf(da, h, vdt[j] * vbm[j] * vxc[j]);
            ap *= da;
        }
        pdt += (ptrdiff_t)SGN * 8 * Dd;
        pxc += (ptrdiff_t)SGN * 8 * Dd;
        pbm += (ptrdiff_t)SGN * 8 * 48;
    }
    int idx = blk * 256 + t;
    aprod[idx] = ap;
    hend[idx]  = h;
}

// Pass 2: serial combine across chunks; overwrite hend with h_start per chunk.
__global__ __launch_bounds__(256) void scan2(
    const float* __restrict__ aprod, float* __restrict__ hend)
{
    int i = blockIdx.x * 256 + threadIdx.x;
    int dn = i & 4095, b = (i >> 12) & 3, dir = i >> 14;
    size_t base = ((size_t)(dir * 4 + b)) * NC * 4096 + dn;
    float h = 0.f;
    for (int c = 0; c < NC; c++) {
        size_t idx = base + (size_t)c * 4096;
        float ap = aprod[idx];
        float hl = hend[idx];
        hend[idx] = h;
        h = fmaf(ap, h, hl);
    }
}

// Pass 3, direction-templated, unroll-8: replay chunk, emit y = (C.h + D*xc)*silu(z)
template<int SGN>
__global__ __launch_bounds__(256) void scan3_t(
    const float* __restrict__ dt, const float* __restrict__ xc,
    const float* __restrict__ dbc, const float* __restrict__ xz,
    const float* __restrict__ Alog, const float* __restrict__ Dparm,
    const float* __restrict__ hstart, float* __restrict__ y,
    int mdir, int zoff, int yoff)
{
    int blk = blockIdx.x;
    int dblk = blk & 15, c = (blk >> 4) & 31, b = blk >> 9;
    int t = threadIdx.x;
    int d = dblk * 16 + (t >> 4), n = t & 15;
    float Ac = -__expf(Alog[d * 16 + n]);
    float Dp = Dparm[d];
    float h = hstart[blk * 256 + t];
    int l0 = (SGN > 0) ? c * LCH : (Ll - 1 - c * LCH);
    size_t bl0 = (size_t)(b * Ll + l0);
    size_t m0 = (size_t)mdir + bl0;
    const float* pdt = dt + m0 * Dd + d;
    const float* pxc = xc + m0 * Dd + d;
    const float* pbm = dbc + m0 * 48 + 16 + n;
    const float* pcm = dbc + m0 * 48 + 32 + n;
    const float* pz  = xz + bl0 * 1024 + zoff + d;
    float*       py  = y  + bl0 * 512  + yoff + d;
    for (int u = 0; u < LCH / 8; ++u) {
        float vdt[8], vxc[8], vbm[8], vcm[8], vz[8];
        #pragma unroll
        for (int j = 0; j < 8; ++j) {
            ptrdiff_t o = (ptrdiff_t)SGN * j;
            vdt[j] = pdt[o * Dd];
            vxc[j] = pxc[o * Dd];
            vbm[j] = pbm[o * 48];
            vcm[j] = pcm[o * 48];
            vz[j]  = pz[o * 1024];
        }
        #pragma unroll
        for (int j = 0; j < 8; ++j) {
            float da = __expf(vdt[j] * Ac);
            h = fmaf(da, h, vdt[j] * vbm[j] * vxc[j]);
            float yp = h * vcm[j];
            yp += __shfl_xor(yp, 1);
            yp += __shfl_xor(yp, 2);
            yp += __shfl_xor(yp, 4);
            yp += __shfl_xor(yp, 8);
            float zv = vz[j];
            float sz = zv / (1.f + __expf(-zv));
            float out = (yp + Dp * vxc[j]) * sz;
            if (n == 0) py[(ptrdiff_t)SGN * j * 512] = out;
        }
        pdt += (ptrdiff_t)SGN * 8 * Dd;
        pxc += (ptrdiff_t)SGN * 8 * Dd;
        pbm += (ptrdiff_t)SGN * 8 * 48;
        pcm += (ptrdiff_t)SGN * 8 * 48;
        pz  += (ptrdiff_t)SGN * 8 * 1024;
        py  += (ptrdiff_t)SGN * 8 * 512;
    }
}

extern "C" void kernel_launch(void* const* d_in, const int* in_sizes, int n_in,
                              void* d_out, int out_size, void* d_ws, size_t ws_size,
                              hipStream_t stream)
{
    const float* x        = (const float*)d_in[0];
    const float* f_in_w   = (const float*)d_in[1];
    const float* f_conv_w = (const float*)d_in[2];
    const float* f_conv_b = (const float*)d_in[3];
    const float* f_xproj  = (const float*)d_in[4];
    const float* f_dt_w   = (const float*)d_in[5];
    const float* f_dt_b   = (const float*)d_in[6];
    const float* f_A_log  = (const float*)d_in[7];
    const float* f_D      = (const float*)d_in[8];
    const float* f_out_w  = (const float*)d_in[9];
    const float* r_in_w   = (const float*)d_in[10];
    const float* r_conv_w = (const float*)d_in[11];
    const float* r_conv_b = (const float*)d_in[12];
    const float* r_xproj  = (const float*)d_in[13];
    const float* r_dt_w   = (const float*)d_in[14];
    const float* r_dt_b   = (const float*)d_in[15];
    const float* r_A_log  = (const float*)d_in[16];
    const float* r_D      = (const float*)d_in[17];
    const float* r_out_w  = (const float*)d_in[18];

    float* ws  = (float*)d_ws;
    float* xz  = ws + OFF_XZ;
    float* xcb = ws + OFF_XC;
    float* dtb = ws + OFF_DT;
    float* dbc = ws + OFF_DBC;
    float* yb  = ws + OFF_Y;
    float* ap  = ws + OFF_AP;
    float* he  = ws + OFF_HE;
    float* W1  = ws + OFF_W1;
    float* W2  = ws + OFF_W2;
    float* B3  = ws + OFF_B3;
    // bf16 plane aliases (regions dead at time of use; see layout comment)
    bf16_t* XH  = (bf16_t*)(ws + OFF_AP);
    bf16_t* XL  = (bf16_t*)(ws + OFF_HE);
    bf16_t* W1H = (bf16_t*)(ws + OFF_Y);
    bf16_t* W1L = (bf16_t*)(ws + OFF_Y + 131072);
    bf16_t* YH  = (bf16_t*)(ws + OFF_XZ);
    bf16_t* YL  = (bf16_t*)(ws + OFF_XZ + 2097152);
    bf16_t* W2H = (bf16_t*)(ws + OFF_AP);
    bf16_t* W2L = (bf16_t*)(ws + OFF_AP + 65536);

    pack_weights<<<512, 256, 0, stream>>>(f_in_w, r_in_w, f_out_w, r_out_w,
                                          f_xproj, r_xproj, W1, W2, B3);

    // In-projection via split-bf16 MFMA: xz = x @ W1^T  [8192x1024]
    cvt_split<<<1024, 256, 0, stream>>>(x,  XH,  XL,  5);   // K=256
    cvt_split<<<128,  256, 0, stream>>>(W1, W1H, W1L, 5);
    gemm_mfma<4, false><<<dim3(8, 64), 256, 0, stream>>>(XH, XL, W1H, W1L, xz, 256, 1024);

    // Conv + SiLU -> xc
    conv_silu_k<<<4096, 256, 0, stream>>>(xz, f_conv_w, f_conv_b, r_conv_w, r_conv_b, xcb);

    // x-projection (small N=48): fp32 GEMM
    gemm_nt<<<dim3(1, 16384 / 64), 256, 0, stream>>>(
        xcb, B3, dbc, 16384, 48, 256, 8192, 48 * 256);

    // dt projection + softplus
    dt_kernel<<<16384, 256, 0, stream>>>(dbc, f_dt_w, f_dt_b, r_dt_w, r_dt_b, dtb);

    // Chunked selective scan (overwrites XH/XL regions — dead by now)
    scan1_t< 1><<<2048, 256, 0, stream>>>(dtb, xcb, dbc, f_A_log, ap, he, 0);
    scan1_t<-1><<<2048, 256, 0, stream>>>(dtb, xcb, dbc, r_A_log,
                                          ap + 2048 * 256, he + 2048 * 256, ML);
    scan2<<<128, 256, 0, stream>>>(ap, he);
    scan3_t< 1><<<2048, 256, 0, stream>>>(dtb, xcb, dbc, xz, f_A_log, f_D,
                                          he, yb, 0, 256, 0);
    scan3_t<-1><<<2048, 256, 0, stream>>>(dtb, xcb, dbc, xz, r_A_log, r_D,
                                          he + 2048 * 256, yb, ML, 512 + 256, 256);

    // Out-projection via split-bf16 MFMA: out = y @ W2^T  [8192x256]
    // A (y) is 128-row-blocked from cvt_split; gemm uses BM=64 -> AHALF=true.
    cvt_split<<<2048, 256, 0, stream>>>(yb, YH,  YL,  6);   // K=512 (xz dead)
    cvt_split<<<64,   256, 0, stream>>>(W2, W2H, W2L, 6);   // (ap dead)
    gemm_mfma<2, true><<<dim3(2, 128), 256, 0, stream>>>(YH, YL, W2H, W2L,
                                                         (float*)d_out, 512, 256);
}

// Round 6
// 299.047 us; speedup vs baseline: 1.4509x; 1.0161x over previous
//
#include <hip/hip_runtime.h>
#include <math.h>

typedef __bf16 bf16_t;
typedef bf16_t bf16x8 __attribute__((ext_vector_type(8)));
typedef float f32x4 __attribute__((ext_vector_type(4)));

// Problem constants
constexpr int Bb = 4, Ll = 2048, Dd = 256, Nn = 16;
constexpr int ML = Bb * Ll;            // 8192 rows (b,l)
constexpr int NC = 32, LCH = Ll / NC;  // 32 chunks of 64

// Workspace layout (float offsets)
constexpr size_t OFF_XZ  = 0;                                   // [8192][1024] xz both dirs
constexpr size_t OFF_XC  = OFF_XZ  + (size_t)ML * 1024;         // [2][8192][256] conv+silu out
constexpr size_t OFF_DT  = OFF_XC  + (size_t)2 * ML * 256;      // [2][8192][256] dt
constexpr size_t OFF_DBC = OFF_DT  + (size_t)2 * ML * 256;      // [16384][48] xproj out
constexpr size_t OFF_Y   = OFF_DBC + (size_t)2 * ML * 48;       // [8192][512] raw y (f|r)
constexpr size_t OFF_AP  = OFF_Y   + (size_t)ML * 512;          // 1M floats chunk A-prod
constexpr size_t OFF_HE  = OFF_AP  + (size_t)2 * Bb * NC * Dd * Nn; // 1M floats
constexpr size_t OFF_W1  = OFF_HE  + (size_t)2 * Bb * NC * Dd * Nn; // [1024][256] packed in_w
constexpr size_t OFF_W2  = OFF_W1  + (size_t)1024 * 256;        // [256][512] packed out_w
constexpr size_t OFF_B3  = OFF_W2  + (size_t)256 * 512;         // [96][256] packed xproj_w
// bf16 plane aliases (all in dead regions at their time of use):
//   XH @ AP, XL @ HE          (consumed by in-proj, then scans overwrite)
//   W1H/W1L @ Y               (consumed by in-proj, scan3 overwrites later)
//   YH/YL @ DT                (written by gate_cvt after scan3; dt dead then.
//                              NOT @ XZ: gate_cvt reads z from xz!)
//   W2H/W2L @ AP              (written after scan2; ap dead then)

__global__ __launch_bounds__(256) void pack_weights(
    const float* __restrict__ f_in_w, const float* __restrict__ r_in_w,
    const float* __restrict__ f_out_w, const float* __restrict__ r_out_w,
    const float* __restrict__ f_xp, const float* __restrict__ r_xp,
    float* __restrict__ W1, float* __restrict__ W2, float* __restrict__ B3)
{
    int i = blockIdx.x * 256 + threadIdx.x;
    if (i < 131072) { W1[i] = f_in_w[i]; W1[131072 + i] = r_in_w[i]; }
    if (i < 65536) {
        int e = i >> 8, k = i & 255;
        W2[e * 512 + k]       = f_out_w[i];
        W2[e * 512 + 256 + k] = r_out_w[i];
    }
    if (i < 12288) { B3[i] = f_xp[i]; B3[12288 + i] = r_xp[i]; }
}

// fp32 [M][K] row-major -> hi/lo bf16 planes in MFMA-blocked layout [m>>7][k>>3][m&127][k&7].
__global__ __launch_bounds__(256) void cvt_split(
    const float* __restrict__ src, bf16_t* __restrict__ dh, bf16_t* __restrict__ dl, int lgK8)
{
    int gid = blockIdx.x * 256 + threadIdx.x;
    int r = gid & 127;
    int tmp = gid >> 7;
    int kbg = tmp & ((1 << lgK8) - 1);
    int mb  = tmp >> lgK8;
    const float* p = src + ((size_t)(mb * 128 + r) << (lgK8 + 3)) + kbg * 8;
    float4 u0 = ((const float4*)p)[0];
    float4 u1 = ((const float4*)p)[1];
    float v[8] = {u0.x, u0.y, u0.z, u0.w, u1.x, u1.y, u1.z, u1.w};
    bf16x8 h8, l8;
    #pragma unroll
    for (int j = 0; j < 8; ++j) {
        bf16_t hb = (bf16_t)v[j];
        float  hf = (float)hb;
        bf16_t lb = (bf16_t)(v[j] - hf);
        h8[j] = hb;
        l8[j] = lb;
    }
    ((bf16x8*)dh)[gid] = h8;
    ((bf16x8*)dl)[gid] = l8;
}

// Fused gate + split-cvt for the out-projection input:
// val = (yraw + Dp*xc) * silu(z), then hi/lo bf16 split into blocked layout (K=512).
__global__ __launch_bounds__(256) void gate_cvt(
    const float* __restrict__ yraw, const float* __restrict__ xc,
    const float* __restrict__ xz,
    const float* __restrict__ fD, const float* __restrict__ rD,
    bf16_t* __restrict__ dh, bf16_t* __restrict__ dl)
{
    int gid = blockIdx.x * 256 + threadIdx.x;   // 2048 blocks
    int r = gid & 127;
    int tmp = gid >> 7;
    int kbg = tmp & 63;          // K=512 -> 64 k-groups
    int mb  = tmp >> 6;
    int bl  = mb * 128 + r;
    int dir = kbg >> 5;          // wave-uniform
    int d0  = (kbg & 31) * 8;
    const float* py  = yraw + (size_t)bl * 512 + dir * 256 + d0;
    const float* pxc = xc + ((size_t)dir * ML + bl) * 256 + d0;
    const float* pz  = xz + (size_t)bl * 1024 + dir * 512 + 256 + d0;
    const float* Dp  = (dir ? rD : fD) + d0;
    float4 y0 = ((const float4*)py)[0],  y1 = ((const float4*)py)[1];
    float4 x0 = ((const float4*)pxc)[0], x1 = ((const float4*)pxc)[1];
    float4 z0 = ((const float4*)pz)[0],  z1 = ((const float4*)pz)[1];
    float4 D0 = ((const float4*)Dp)[0],  D1 = ((const float4*)Dp)[1];
    float vy[8] = {y0.x, y0.y, y0.z, y0.w, y1.x, y1.y, y1.z, y1.w};
    float vx[8] = {x0.x, x0.y, x0.z, x0.w, x1.x, x1.y, x1.z, x1.w};
    float vz[8] = {z0.x, z0.y, z0.z, z0.w, z1.x, z1.y, z1.z, z1.w};
    float vD[8] = {D0.x, D0.y, D0.z, D0.w, D1.x, D1.y, D1.z, D1.w};
    bf16x8 h8, l8;
    #pragma unroll
    for (int j = 0; j < 8; ++j) {
        float sz = vz[j] / (1.f + __expf(-vz[j]));
        float v  = (vy[j] + vD[j] * vx[j]) * sz;
        bf16_t hb = (bf16_t)v;
        float  hf = (float)hb;
        h8[j] = hb;
        l8[j] = (bf16_t)(v - hf);
    }
    ((bf16x8*)dh)[gid] = h8;
    ((bf16x8*)dl)[gid] = l8;
}

// Split-bf16 MFMA GEMM: C[M][N] = (Ah+Al)[M][K] * (Bh+Bl)[N][K]^T (3-term, fp32 acc).
template<int FI, bool AHALF>   // FI = BM/32 : 4 -> BM=128, 2 -> BM=64
__global__ __launch_bounds__(256) void gemm_mfma(
    const bf16_t* __restrict__ Ahg, const bf16_t* __restrict__ Alg,
    const bf16_t* __restrict__ Bhg, const bf16_t* __restrict__ Blg,
    float* __restrict__ C, int K, int N)
{
    constexpr int BM = FI * 32;
    constexpr int AE = 32 * BM;
    constexpr int BE = 32 * 128;
    constexpr int CA = AE / 512;
    constexpr int CB = BE / 512;
    constexpr int NCH = 2 * CA + 2 * CB;
    constexpr int QC = NCH / 4;
    __shared__ alignas(16) bf16_t sAh[AE], sAl[AE], sBh[BE], sBl[BE];
    const int t = threadIdx.x, w = t >> 6, l = t & 63;
    const int mb = blockIdx.y, nb = blockIdx.x;
    const int K8 = K >> 3;
    const int wm = w >> 1, wn = w & 1;
    const int lr = l & 15, kb = l >> 4;
    const size_t aoff = AHALF ? ((size_t)(mb >> 1) * K8 * (128 * 8) + (size_t)(mb & 1) * 512)
                              : (size_t)mb * K8 * (BM * 8);
    const size_t boff = (size_t)nb * K8 * (128 * 8);

    auto gsrc = [&](int c, int ks) -> const bf16_t* {
        if (c < 2 * CA) {
            const bf16_t* base = (c < CA) ? Ahg : Alg;
            int ca = (c < CA) ? c : c - CA;
            if (AHALF) return base + aoff + (size_t)(ks * CA + ca) * (128 * 8);
            else       return base + aoff + (size_t)ks * AE + ca * 512;
        } else {
            const bf16_t* base = (c < 2 * CA + CB) ? Bhg : Blg;
            int cbn = (c < 2 * CA + CB) ? (c - 2 * CA) : (c - 2 * CA - CB);
            return base + boff + (size_t)ks * BE + cbn * 512;
        }
    };
    auto sdst = [&](int c) -> bf16_t* {
        if (c < CA)              return sAh + c * 512;
        else if (c < 2 * CA)     return sAl + (c - CA) * 512;
        else if (c < 2 * CA + CB) return sBh + (c - 2 * CA) * 512;
        else                     return sBl + (c - 2 * CA - CB) * 512;
    };

    f32x4 acc[FI][4] = {};
    bf16x8 vst[QC];
    #pragma unroll
    for (int q = 0; q < QC; ++q)
        vst[q] = *(const bf16x8*)(gsrc(w + q * 4, 0) + l * 8);

    const int KS = K / 32;
    for (int ks = 0;; ++ks) {
        __syncthreads();
        #pragma unroll
        for (int q = 0; q < QC; ++q)
            *(bf16x8*)(sdst(w + q * 4) + l * 8) = vst[q];
        __syncthreads();
        if (ks + 1 < KS) {
            #pragma unroll
            for (int q = 0; q < QC; ++q)
                vst[q] = *(const bf16x8*)(gsrc(w + q * 4, ks + 1) + l * 8);
        }
        bf16x8 ah[FI], al[FI], bh[4], bl[4];
        #pragma unroll
        for (int i = 0; i < FI; ++i) {
            int row = wm * (FI * 16) + i * 16 + lr;
            ah[i] = *(const bf16x8*)(sAh + (kb * BM + row) * 8);
            al[i] = *(const bf16x8*)(sAl + (kb * BM + row) * 8);
        }
        #pragma unroll
        for (int j = 0; j < 4; ++j) {
            int col = wn * 64 + j * 16 + lr;
            bh[j] = *(const bf16x8*)(sBh + (kb * 128 + col) * 8);
            bl[j] = *(const bf16x8*)(sBl + (kb * 128 + col) * 8);
        }
        #pragma unroll
        for (int i = 0; i < FI; ++i)
            #pragma unroll
            for (int j = 0; j < 4; ++j) {
                acc[i][j] = __builtin_amdgcn_mfma_f32_16x16x32_bf16(ah[i], bh[j], acc[i][j], 0, 0, 0);
                acc[i][j] = __builtin_amdgcn_mfma_f32_16x16x32_bf16(ah[i], bl[j], acc[i][j], 0, 0, 0);
                acc[i][j] = __builtin_amdgcn_mfma_f32_16x16x32_bf16(al[i], bh[j], acc[i][j], 0, 0, 0);
            }
        if (ks + 1 == KS) break;
    }
    #pragma unroll
    for (int i = 0; i < FI; ++i)
        #pragma unroll
        for (int p = 0; p < 4; ++p) {
            int m = mb * BM + wm * (FI * 16) + i * 16 + kb * 4 + p;
            float* cp = C + (size_t)m * N + nb * 128 + wn * 64 + lr;
            #pragma unroll
            for (int j = 0; j < 4; ++j) cp[j * 16] = acc[i][j][p];
        }
}

// Generic fp32 NT GEMM (kept for the small xproj: N=48).
__global__ __launch_bounds__(256) void gemm_nt(
    const float* __restrict__ A, const float* __restrict__ Bmat,
    float* __restrict__ C, int M, int N, int K, int bSwitchM, int bAltOff)
{
    constexpr int BM = 64, BN = 64, BK = 32, PK = 36;
    __shared__ float As[BM * PK];
    __shared__ float Bs[BN * PK];
    int m0 = blockIdx.y * BM, n0 = blockIdx.x * BN;
    const float* Bp = Bmat + ((m0 >= bSwitchM) ? bAltOff : 0);
    int t  = threadIdx.x;
    int tx = t & 15, ty = t >> 4;
    int lr  = t >> 3;
    int lc4 = (t & 7) * 4;
    float acc[4][4] = {};
    for (int k0 = 0; k0 < K; k0 += BK) {
        float4 av0 = *(const float4*)(A + (size_t)(m0 + lr)      * K + k0 + lc4);
        float4 av1 = *(const float4*)(A + (size_t)(m0 + lr + 32) * K + k0 + lc4);
        float4 bv0 = make_float4(0.f, 0.f, 0.f, 0.f), bv1 = bv0;
        if (n0 + lr      < N) bv0 = *(const float4*)(Bp + (size_t)(n0 + lr)      * K + k0 + lc4);
        if (n0 + lr + 32 < N) bv1 = *(const float4*)(Bp + (size_t)(n0 + lr + 32) * K + k0 + lc4);
        __syncthreads();
        *(float4*)(As + lr * PK + lc4)        = av0;
        *(float4*)(As + (lr + 32) * PK + lc4) = av1;
        *(float4*)(Bs + lr * PK + lc4)        = bv0;
        *(float4*)(Bs + (lr + 32) * PK + lc4) = bv1;
        __syncthreads();
        #pragma unroll
        for (int kq = 0; kq < BK / 4; ++kq) {
            float4 a4[4], b4[4];
            #pragma unroll
            for (int i = 0; i < 4; i++) a4[i] = *(const float4*)(As + (ty + i * 16) * PK + kq * 4);
            #pragma unroll
            for (int j = 0; j < 4; j++) b4[j] = *(const float4*)(Bs + (tx + j * 16) * PK + kq * 4);
            #pragma unroll
            for (int i = 0; i < 4; i++)
                #pragma unroll
                for (int j = 0; j < 4; j++)
                    acc[i][j] += a4[i].x * b4[j].x + a4[i].y * b4[j].y +
                                 a4[i].z * b4[j].z + a4[i].w * b4[j].w;
        }
    }
    #pragma unroll
    for (int i = 0; i < 4; i++) {
        int m = m0 + ty + i * 16;
        #pragma unroll
        for (int j = 0; j < 4; j++) {
            int n = n0 + tx + j * 16;
            if (n < N) C[(size_t)m * N + n] = acc[i][j];
        }
    }
}

// Depthwise conv width-2 + SiLU. dir 0 taps (l-1, l); dir 1 taps (l+1, l).
__global__ __launch_bounds__(256) void conv_silu_k(
    const float* __restrict__ xz,
    const float* __restrict__ fw, const float* __restrict__ fb,
    const float* __restrict__ rw, const float* __restrict__ rb,
    float* __restrict__ xc)
{
    int i = blockIdx.x * 256 + threadIdx.x;
    int dir = i >> 19;
    int r   = i & 524287;
    int bl  = r >> 6;
    int l   = bl & 2047;
    int d4  = (r & 63) * 4;
    const float* cw = dir ? rw : fw;
    const float* cb = dir ? rb : fb;
    size_t rowc = (size_t)bl * 1024 + dir * 512 + d4;
    float4 cur = *(const float4*)(xz + rowc);
    float4 prv = make_float4(0.f, 0.f, 0.f, 0.f);
    if (dir == 0) { if (l > 0)      prv = *(const float4*)(xz + rowc - 1024); }
    else          { if (l < Ll - 1) prv = *(const float4*)(xz + rowc + 1024); }
    float pv[4] = {prv.x, prv.y, prv.z, prv.w};
    float cv[4] = {cur.x, cur.y, cur.z, cur.w};
    float out[4];
    #pragma unroll
    for (int j = 0; j < 4; j++) {
        float v = pv[j] * cw[(d4 + j) * 2] + cv[j] * cw[(d4 + j) * 2 + 1] + cb[d4 + j];
        out[j] = v / (1.f + __expf(-v));
    }
    *(float4*)(xc + (size_t)(dir * ML + bl) * 256 + d4) = make_float4(out[0], out[1], out[2], out[3]);
}

// dt[d] = softplus(sum_r dbc[r]*dt_w[d,r] + dt_b[d])
__global__ __launch_bounds__(256) void dt_kernel(
    const float* __restrict__ dbc,
    const float* __restrict__ fw, const float* __restrict__ fb,
    const float* __restrict__ rw, const float* __restrict__ rb,
    float* __restrict__ dt)
{
    int m = blockIdx.x;
    int d = threadIdx.x;
    int dir = m >> 13;
    __shared__ float s[16];
    if (d < 16) s[d] = dbc[(size_t)m * 48 + d];
    __syncthreads();
    const float* w = (dir ? rw : fw) + d * 16;
    float acc = (dir ? rb : fb)[d];
    #pragma unroll
    for (int r = 0; r < 16; r++) acc += s[r] * w[r];
    float sp = (acc > 20.f) ? acc : log1pf(__expf(acc));
    dt[(size_t)m * 256 + d] = sp;
}

// Chunked scan pass 1, direction-templated, 2 chunk-streams per thread, unroll-8.
// blk = b*256 + cp*16 + dblk handles chunks cp and cp+16.
template<int SGN>
__global__ __launch_bounds__(256) void scan1_t(
    const float* __restrict__ dt, const float* __restrict__ xc,
    const float* __restrict__ dbc, const float* __restrict__ Alog,
    float* __restrict__ aprod, float* __restrict__ hend, int mdir)
{
    int blk = blockIdx.x;                 // 0..1023 per dir
    int dblk = blk & 15, cp = (blk >> 4) & 15, b = blk >> 8;
    int t = threadIdx.x;
    int d = dblk * 16 + (t >> 4), n = t & 15;
    float Ac = -__expf(Alog[d * 16 + n]);
    int c0 = cp, c1 = cp + 16;
    int l00 = (SGN > 0) ? c0 * LCH : (Ll - 1 - c0 * LCH);
    int l01 = (SGN > 0) ? c1 * LCH : (Ll - 1 - c1 * LCH);
    size_t m00 = (size_t)(mdir + b * Ll + l00);
    size_t m01 = (size_t)(mdir + b * Ll + l01);
    const float *pdt0 = dt + m00 * Dd + d,        *pdt1 = dt + m01 * Dd + d;
    const float *pxc0 = xc + m00 * Dd + d,        *pxc1 = xc + m01 * Dd + d;
    const float *pbm0 = dbc + m00 * 48 + 16 + n,  *pbm1 = dbc + m01 * 48 + 16 + n;
    float h0 = 0.f, ap0 = 1.f, h1 = 0.f, ap1 = 1.f;
    for (int u = 0; u < LCH / 8; ++u) {
        float vdt0[8], vxc0[8], vbm0[8], vdt1[8], vxc1[8], vbm1[8];
        #pragma unroll
        for (int j = 0; j < 8; ++j) {
            ptrdiff_t o = (ptrdiff_t)SGN * j;
            vdt0[j] = pdt0[o * Dd];  vdt1[j] = pdt1[o * Dd];
            vxc0[j] = pxc0[o * Dd];  vxc1[j] = pxc1[o * Dd];
            vbm0[j] = pbm0[o * 48];  vbm1[j] = pbm1[o * 48];
        }
        #pragma unroll
        for (int j = 0; j < 8; ++j) {
            float da0 = __expf(vdt0[j] * Ac);
            float da1 = __expf(vdt1[j] * Ac);
            h0 = fmaf(da0, h0, vdt0[j] * vbm0[j] * vxc0[j]);
            h1 = fmaf(da1, h1, vdt1[j] * vbm1[j] * vxc1[j]);
            ap0 *= da0;
            ap1 *= da1;
        }
        pdt0 += (ptrdiff_t)SGN * 8 * Dd;  pdt1 += (ptrdiff_t)SGN * 8 * Dd;
        pxc0 += (ptrdiff_t)SGN * 8 * Dd;  pxc1 += (ptrdiff_t)SGN * 8 * Dd;
        pbm0 += (ptrdiff_t)SGN * 8 * 48;  pbm1 += (ptrdiff_t)SGN * 8 * 48;
    }
    int idx0 = (b * 512 + c0 * 16 + dblk) * 256 + t;
    int idx1 = (b * 512 + c1 * 16 + dblk) * 256 + t;
    aprod[idx0] = ap0;  hend[idx0] = h0;
    aprod[idx1] = ap1;  hend[idx1] = h1;
}

// Pass 2: serial combine across chunks; overwrite hend with h_start per chunk.
__global__ __launch_bounds__(256) void scan2(
    const float* __restrict__ aprod, float* __restrict__ hend)
{
    int i = blockIdx.x * 256 + threadIdx.x;
    int dn = i & 4095, b = (i >> 12) & 3, dir = i >> 14;
    size_t base = ((size_t)(dir * 4 + b)) * NC * 4096 + dn;
    float h = 0.f;
    for (int c = 0; c < NC; c++) {
        size_t idx = base + (size_t)c * 4096;
        float ap = aprod[idx];
        float hl = hend[idx];
        hend[idx] = h;
        h = fmaf(ap, h, hl);
    }
}

// Pass 3, 2 chunk-streams per thread: replay from h_start, emit RAW yp = C.h
// (gating (yp + D*xc)*silu(z) moved to gate_cvt).
template<int SGN>
__global__ __launch_bounds__(256) void scan3_t(
    const float* __restrict__ dt, const float* __restrict__ xc,
    const float* __restrict__ dbc, const float* __restrict__ Alog,
    const float* __restrict__ hstart, float* __restrict__ y,
    int mdir, int yoff)
{
    int blk = blockIdx.x;
    int dblk = blk & 15, cp = (blk >> 4) & 15, b = blk >> 8;
    int t = threadIdx.x;
    int d = dblk * 16 + (t >> 4), n = t & 15;
    float Ac = -__expf(Alog[d * 16 + n]);
    int c0 = cp, c1 = cp + 16;
    int idx0 = (b * 512 + c0 * 16 + dblk) * 256 + t;
    int idx1 = (b * 512 + c1 * 16 + dblk) * 256 + t;
    float h0 = hstart[idx0];
    float h1 = hstart[idx1];
    int l00 = (SGN > 0) ? c0 * LCH : (Ll - 1 - c0 * LCH);
    int l01 = (SGN > 0) ? c1 * LCH : (Ll - 1 - c1 * LCH);
    size_t bl00 = (size_t)(b * Ll + l00);
    size_t bl01 = (size_t)(b * Ll + l01);
    size_t m00 = (size_t)mdir + bl00;
    size_t m01 = (size_t)mdir + bl01;
    const float *pdt0 = dt + m00 * Dd + d,       *pdt1 = dt + m01 * Dd + d;
    const float *pxc0 = xc + m00 * Dd + d,       *pxc1 = xc + m01 * Dd + d;
    const float *pbm0 = dbc + m00 * 48 + 16 + n, *pbm1 = dbc + m01 * 48 + 16 + n;
    const float *pcm0 = dbc + m00 * 48 + 32 + n, *pcm1 = dbc + m01 * 48 + 32 + n;
    float *py0 = y + bl00 * 512 + yoff + d;
    float *py1 = y + bl01 * 512 + yoff + d;
    for (int u = 0; u < LCH / 8; ++u) {
        float vdt0[8], vxc0[8], vbm0[8], vcm0[8];
        float vdt1[8], vxc1[8], vbm1[8], vcm1[8];
        #pragma unroll
        for (int j = 0; j < 8; ++j) {
            ptrdiff_t o = (ptrdiff_t)SGN * j;
            vdt0[j] = pdt0[o * Dd];  vdt1[j] = pdt1[o * Dd];
            vxc0[j] = pxc0[o * Dd];  vxc1[j] = pxc1[o * Dd];
            vbm0[j] = pbm0[o * 48];  vbm1[j] = pbm1[o * 48];
            vcm0[j] = pcm0[o * 48];  vcm1[j] = pcm1[o * 48];
        }
        #pragma unroll
        for (int j = 0; j < 8; ++j) {
            float da0 = __expf(vdt0[j] * Ac);
            float da1 = __expf(vdt1[j] * Ac);
            h0 = fmaf(da0, h0, vdt0[j] * vbm0[j] * vxc0[j]);
            h1 = fmaf(da1, h1, vdt1[j] * vbm1[j] * vxc1[j]);
            float yp0 = h0 * vcm0[j];
            float yp1 = h1 * vcm1[j];
            yp0 += __shfl_xor(yp0, 1);  yp1 += __shfl_xor(yp1, 1);
            yp0 += __shfl_xor(yp0, 2);  yp1 += __shfl_xor(yp1, 2);
            yp0 += __shfl_xor(yp0, 4);  yp1 += __shfl_xor(yp1, 4);
            yp0 += __shfl_xor(yp0, 8);  yp1 += __shfl_xor(yp1, 8);
            if (n == 0) {
                py0[(ptrdiff_t)SGN * j * 512] = yp0;
                py1[(ptrdiff_t)SGN * j * 512] = yp1;
            }
        }
        pdt0 += (ptrdiff_t)SGN * 8 * Dd;  pdt1 += (ptrdiff_t)SGN * 8 * Dd;
        pxc0 += (ptrdiff_t)SGN * 8 * Dd;  pxc1 += (ptrdiff_t)SGN * 8 * Dd;
        pbm0 += (ptrdiff_t)SGN * 8 * 48;  pbm1 += (ptrdiff_t)SGN * 8 * 48;
        pcm0 += (ptrdiff_t)SGN * 8 * 48;  pcm1 += (ptrdiff_t)SGN * 8 * 48;
        py0  += (ptrdiff_t)SGN * 8 * 512; py1  += (ptrdiff_t)SGN * 8 * 512;
    }
}

extern "C" void kernel_launch(void* const* d_in, const int* in_sizes, int n_in,
                              void* d_out, int out_size, void* d_ws, size_t ws_size,
                              hipStream_t stream)
{
    const float* x        = (const float*)d_in[0];
    const float* f_in_w   = (const float*)d_in[1];
    const float* f_conv_w = (const float*)d_in[2];
    const float* f_conv_b = (const float*)d_in[3];
    const float* f_xproj  = (const float*)d_in[4];
    const float* f_dt_w   = (const float*)d_in[5];
    const float* f_dt_b   = (const float*)d_in[6];
    const float* f_A_log  = (const float*)d_in[7];
    const float* f_D      = (const float*)d_in[8];
    const float* f_out_w  = (const float*)d_in[9];
    const float* r_in_w   = (const float*)d_in[10];
    const float* r_conv_w = (const float*)d_in[11];
    const float* r_conv_b = (const float*)d_in[12];
    const float* r_xproj  = (const float*)d_in[13];
    const float* r_dt_w   = (const float*)d_in[14];
    const float* r_dt_b   = (const float*)d_in[15];
    const float* r_A_log  = (const float*)d_in[16];
    const float* r_D      = (const float*)d_in[17];
    const float* r_out_w  = (const float*)d_in[18];

    float* ws  = (float*)d_ws;
    float* xz  = ws + OFF_XZ;
    float* xcb = ws + OFF_XC;
    float* dtb = ws + OFF_DT;
    float* dbc = ws + OFF_DBC;
    float* yb  = ws + OFF_Y;
    float* ap  = ws + OFF_AP;
    float* he  = ws + OFF_HE;
    float* W1  = ws + OFF_W1;
    float* W2  = ws + OFF_W2;
    float* B3  = ws + OFF_B3;
    // bf16 plane aliases (regions dead at time of use; see layout comment)
    bf16_t* XH  = (bf16_t*)(ws + OFF_AP);
    bf16_t* XL  = (bf16_t*)(ws + OFF_HE);
    bf16_t* W1H = (bf16_t*)(ws + OFF_Y);
    bf16_t* W1L = (bf16_t*)(ws + OFF_Y + 131072);
    bf16_t* YH  = (bf16_t*)(ws + OFF_DT);              // dt dead after scan3
    bf16_t* YL  = (bf16_t*)(ws + OFF_DT + 2097152);
    bf16_t* W2H = (bf16_t*)(ws + OFF_AP);
    bf16_t* W2L = (bf16_t*)(ws + OFF_AP + 65536);

    pack_weights<<<512, 256, 0, stream>>>(f_in_w, r_in_w, f_out_w, r_out_w,
                                          f_xproj, r_xproj, W1, W2, B3);

    // In-projection via split-bf16 MFMA: xz = x @ W1^T  [8192x1024]
    cvt_split<<<1024, 256, 0, stream>>>(x,  XH,  XL,  5);   // K=256
    cvt_split<<<128,  256, 0, stream>>>(W1, W1H, W1L, 5);
    gemm_mfma<4, false><<<dim3(8, 64), 256, 0, stream>>>(XH, XL, W1H, W1L, xz, 256, 1024);

    // Conv + SiLU -> xc
    conv_silu_k<<<4096, 256, 0, stream>>>(xz, f_conv_w, f_conv_b, r_conv_w, r_conv_b, xcb);

    // x-projection (small N=48): fp32 GEMM
    gemm_nt<<<dim3(1, 16384 / 64), 256, 0, stream>>>(
        xcb, B3, dbc, 16384, 48, 256, 8192, 48 * 256);

    // dt projection + softplus
    dt_kernel<<<16384, 256, 0, stream>>>(dbc, f_dt_w, f_dt_b, r_dt_w, r_dt_b, dtb);

    // Chunked selective scan (2 chunk-streams/thread -> 1024 blocks per dir)
    scan1_t< 1><<<1024, 256, 0, stream>>>(dtb, xcb, dbc, f_A_log, ap, he, 0);
    scan1_t<-1><<<1024, 256, 0, stream>>>(dtb, xcb, dbc, r_A_log,
                                          ap + 2048 * 256, he + 2048 * 256, ML);
    scan2<<<128, 256, 0, stream>>>(ap, he);
    scan3_t< 1><<<1024, 256, 0, stream>>>(dtb, xcb, dbc, f_A_log, he, yb, 0, 0);
    scan3_t<-1><<<1024, 256, 0, stream>>>(dtb, xcb, dbc, r_A_log,
                                          he + 2048 * 256, yb, ML, 256);

    // Out-projection: gate+cvt fused, then split-bf16 MFMA: out = gated(y) @ W2^T
    gate_cvt<<<2048, 256, 0, stream>>>(yb, xcb, xz, f_D, r_D, YH, YL);
    cvt_split<<<64, 256, 0, stream>>>(W2, W2H, W2L, 6);
    gemm_mfma<2, true><<<dim3(2, 128), 256, 0, stream>>>(YH, YL, W2H, W2L,
                                                         (float*)d_out, 512, 256);
}